// Round 2
// baseline (121.496 us; speedup 1.0000x reference)
//
#include <hip/hip_runtime.h>
#include <stdint.h>

#define BB 4
#define NN 2048
#define F_IN 128
#define F_OUT 256
#define NH 4
#define HD 64

typedef float f32x4 __attribute__((ext_vector_type(4)));
typedef short s16x8 __attribute__((ext_vector_type(8)));
typedef int i32x4 __attribute__((ext_vector_type(4)));
typedef unsigned short u16;

__device__ __forceinline__ u16 f32_to_bf16_rtn(float f) {
    union { float f; uint32_t u; } v; v.f = f;
    uint32_t u = v.u;
    u += 0x7fffu + ((u >> 16) & 1u);
    return (u16)(u >> 16);
}

// K1: h = x @ W^T (fp32). 8-row n-tiles, 1024 blocks (50% occupancy).
// Stores hT bf16 [B, F_OUT, N]; e_l/e_r via wave butterfly (wave w = head w).
__global__ __launch_bounds__(256) void k1_proj(
    const float* __restrict__ x, const float* __restrict__ W,
    const float* __restrict__ a_l, const float* __restrict__ a_r,
    u16* __restrict__ hT, float* __restrict__ el, float* __restrict__ er)
{
    const int t = threadIdx.x;
    const int b = blockIdx.x >> 8;            // 256 n-tiles per batch
    const int n0 = (blockIdx.x & 255) * 8;

    __shared__ __align__(16) float xs[8][F_IN];   // 4 KB
    {
        const f32x4* src = (const f32x4*)(x + ((size_t)b * NN + n0) * F_IN);
        ((f32x4*)&xs[0][0])[t] = src[t];          // 256 f32x4 = 4 KB
    }
    __syncthreads();

    float acc[8];
#pragma unroll
    for (int n = 0; n < 8; ++n) acc[n] = 0.f;

    const float* wrow = W + (size_t)t * F_IN;
#pragma unroll 4
    for (int k0 = 0; k0 < F_IN; k0 += 8) {
        f32x4 w0 = *(const f32x4*)(wrow + k0);
        f32x4 w1 = *(const f32x4*)(wrow + k0 + 4);
#pragma unroll
        for (int n = 0; n < 8; ++n) {
            f32x4 xa = *(const f32x4*)&xs[n][k0];       // wave-uniform: LDS broadcast
            f32x4 xb = *(const f32x4*)&xs[n][k0 + 4];
            float s = acc[n];
            s = fmaf(xa[0], w0[0], s); s = fmaf(xa[1], w0[1], s);
            s = fmaf(xa[2], w0[2], s); s = fmaf(xa[3], w0[3], s);
            s = fmaf(xb[0], w1[0], s); s = fmaf(xb[1], w1[1], s);
            s = fmaf(xb[2], w1[2], s); s = fmaf(xb[3], w1[3], s);
            acc[n] = s;
        }
    }

    // e_l / e_r: wave w covers head w's 64 dims; butterfly over lanes.
    const int w = t >> 6, lane = t & 63;
    const float al = a_l[t];
    const float ar = a_r[t];
    float my_el = 0.f, my_er = 0.f;
#pragma unroll
    for (int n = 0; n < 8; ++n) {
        float vl = acc[n] * al;
        float vr = acc[n] * ar;
#pragma unroll
        for (int off = 32; off; off >>= 1) {
            vl += __shfl_xor(vl, off, 64);
            vr += __shfl_xor(vr, off, 64);
        }
        if (lane == n) { my_el = vl; my_er = vr; }
    }
    if (lane < 8) {
        el[((size_t)b * NH + w) * NN + n0 + lane] = my_el;
        er[((size_t)b * NH + w) * NN + n0 + lane] = my_er;
    }

    u16* hrow = hT + ((size_t)b * F_OUT + t) * NN + n0;
    s16x8 pk;
#pragma unroll
    for (int n = 0; n < 8; ++n) pk[n] = (short)f32_to_bf16_rtn(acc[n]);
    *(s16x8*)hrow = pk;
}

// K2: fused masked softmax + aggregation.
// Block = (b, 32-row i-tile), 16 waves: wave = (jchunk c, rowhalf rh, head w).
// Distance-1 register prefetch in the j-loop; LDS reduce over the 2 j-chunks.
#define JS 2
#define NIT (NN / JS / 32)   // 32

__global__ __launch_bounds__(1024, 4) void k2_attn(
    const int* __restrict__ adj, const u16* __restrict__ hT,
    const float* __restrict__ el, const float* __restrict__ er,
    float* __restrict__ out)
{
    const int t = threadIdx.x;
    const int wave = t >> 6, l = t & 63;
    const int w = wave & 3;              // head
    const int rh = (wave >> 2) & 1;      // row half of the 32-row tile
    const int c = wave >> 3;             // j chunk
    int bid = blockIdx.x;
    bid = (bid & 7) * 32 + (bid >> 3);   // XCD swizzle (256 % 8 == 0, bijective)
    const int b = bid >> 6;
    const int i0 = (bid & 63) * 32;
    const int r = l & 15;                // A row / D col index
    const int ks = (l >> 4) * 8;         // k-slice within 32-j step
    const int irow = i0 + rh * 16 + r;
    const int j0 = c * (NN / JS);

    const float el_i = el[((size_t)b * NH + w) * NN + irow];
    const float* erp = er + ((size_t)b * NH + w) * NN + j0 + ks;
    const int*  adjp = adj + ((size_t)b * NN + irow) * NN + j0 + ks;
    const u16*  hp   = hT + ((size_t)b * F_OUT + w * HD + r) * NN + j0 + ks;

    f32x4 acc0 = {0.f,0.f,0.f,0.f}, acc1 = acc0, acc2 = acc0, acc3 = acc0;
    float rowsum = 0.f;

    // prologue loads
    i32x4 a0 = *(const i32x4*)adjp;
    i32x4 a1 = *(const i32x4*)(adjp + 4);
    f32x4 e0 = *(const f32x4*)erp;
    f32x4 e1 = *(const f32x4*)(erp + 4);
    s16x8 b0 = *(const s16x8*)(hp);
    s16x8 b1 = *(const s16x8*)(hp + 16 * NN);
    s16x8 b2 = *(const s16x8*)(hp + 32 * NN);
    s16x8 b3 = *(const s16x8*)(hp + 48 * NN);

    for (int jt = 0; jt < NIT; ++jt) {
        i32x4 ca0 = a0, ca1 = a1;
        f32x4 ce0 = e0, ce1 = e1;
        s16x8 cb0 = b0, cb1 = b1, cb2 = b2, cb3 = b3;
        if (jt + 1 < NIT) {              // issue next iter's loads early
            adjp += 32; erp += 32; hp += 32;
            a0 = *(const i32x4*)adjp;
            a1 = *(const i32x4*)(adjp + 4);
            e0 = *(const f32x4*)erp;
            e1 = *(const f32x4*)(erp + 4);
            b0 = *(const s16x8*)(hp);
            b1 = *(const s16x8*)(hp + 16 * NN);
            b2 = *(const s16x8*)(hp + 32 * NN);
            b3 = *(const s16x8*)(hp + 48 * NN);
        }

        s16x8 afrag;
#pragma unroll
        for (int k = 0; k < 8; ++k) {
            float e_j = (k < 4) ? ce0[k] : ce1[k - 4];
            int   av  = (k < 4) ? ca0[k] : ca1[k - 4];
            float s = el_i + e_j;
            s = fmaxf(s, 0.2f * s);          // leaky_relu(0.2)
            float pe = __expf(s);
            pe = av ? pe : 0.f;              // adjacency mask
            rowsum += pe;
            afrag[k] = (short)f32_to_bf16_rtn(pe);
        }

        acc0 = __builtin_amdgcn_mfma_f32_16x16x32_bf16(afrag, cb0, acc0, 0, 0, 0);
        acc1 = __builtin_amdgcn_mfma_f32_16x16x32_bf16(afrag, cb1, acc1, 0, 0, 0);
        acc2 = __builtin_amdgcn_mfma_f32_16x16x32_bf16(afrag, cb2, acc2, 0, 0, 0);
        acc3 = __builtin_amdgcn_mfma_f32_16x16x32_bf16(afrag, cb3, acc3, 0, 0, 0);
    }

    // intra-wave rowsum: combine the 4 k-slice lanes sharing (l&15)
    rowsum += __shfl_xor(rowsum, 16, 64);
    rowsum += __shfl_xor(rowsum, 32, 64);

    __shared__ __align__(16) float racc[8][64][20];   // +4 pad: kill 64B-stride conflicts
    __shared__ float rsum[16][16];

    if (l < 16) rsum[wave][l] = rowsum;
    if (c == 1) {
        float* p = &racc[wave - 8][l][0];
        *(f32x4*)(p + 0) = acc0; *(f32x4*)(p + 4)  = acc1;
        *(f32x4*)(p + 8) = acc2; *(f32x4*)(p + 12) = acc3;
    }
    __syncthreads();
    if (c == 0) {
        const float* p = &racc[wave][l][0];
        acc0 += *(const f32x4*)(p + 0); acc1 += *(const f32x4*)(p + 4);
        acc2 += *(const f32x4*)(p + 8); acc3 += *(const f32x4*)(p + 12);

        float* op = out + ((size_t)b * NN + i0 + rh * 16) * F_OUT + w * HD;
#pragma unroll
        for (int q = 0; q < 4; ++q) {
            const int row = (l >> 4) * 4 + q;
            float rs = rsum[wave][row] + rsum[wave + 8][row];
            float inv = 1.0f / rs;
            op[(size_t)row * F_OUT +  0 + r] = acc0[q] * inv;
            op[(size_t)row * F_OUT + 16 + r] = acc1[q] * inv;
            op[(size_t)row * F_OUT + 32 + r] = acc2[q] * inv;
            op[(size_t)row * F_OUT + 48 + r] = acc3[q] * inv;
        }
    }
}

extern "C" void kernel_launch(void* const* d_in, const int* in_sizes, int n_in,
                              void* d_out, int out_size, void* d_ws, size_t ws_size,
                              hipStream_t stream) {
    const float* x   = (const float*)d_in[0];
    const int*   adj = (const int*)d_in[1];
    const float* W   = (const float*)d_in[2];
    const float* a_l = (const float*)d_in[3];
    const float* a_r = (const float*)d_in[4];
    float* out = (float*)d_out;

    u16*   hT = (u16*)d_ws;
    float* el = (float*)((char*)d_ws + (size_t)BB * F_OUT * NN * sizeof(u16));
    float* er = el + (size_t)BB * NH * NN;

    k1_proj<<<BB * (NN / 8), 256, 0, stream>>>(x, W, a_l, a_r, hT, el, er);
    k2_attn<<<BB * (NN / 32), 1024, 0, stream>>>(adj, hT, el, er, out);
}

// Round 3
// 86.943 us; speedup vs baseline: 1.3974x; 1.3974x over previous
//
#include <hip/hip_runtime.h>
#include <stdint.h>

#define BB 4
#define NN 2048
#define F_IN 128
#define F_OUT 256
#define NH 4
#define HD 64
#define NT 32            // 32 j-tiles of 64 columns
#define TILE_B 32768     // staged hT tile: 256 rows x 128 B

typedef float f32x4 __attribute__((ext_vector_type(4)));
typedef short s16x8 __attribute__((ext_vector_type(8)));
typedef int i32x4 __attribute__((ext_vector_type(4)));
typedef unsigned short u16;

__device__ __forceinline__ u16 f32_to_bf16_rtn(float f) {
    union { float f; uint32_t u; } v; v.f = f;
    uint32_t u = v.u;
    u += 0x7fffu + ((u >> 16) & 1u);
    return (u16)(u >> 16);
}

__device__ __forceinline__ void gload16(const void* g, void* l) {
    __builtin_amdgcn_global_load_lds(
        (const __attribute__((address_space(1))) unsigned int*)g,
        (__attribute__((address_space(3))) unsigned int*)l, 16, 0, 0);
}

// K1: h = x @ W^T (fp32). 16-row n-tiles, 512 blocks.
__global__ __launch_bounds__(256, 2) void k1_proj(
    const float* __restrict__ x, const float* __restrict__ W,
    const float* __restrict__ a_l, const float* __restrict__ a_r,
    u16* __restrict__ hT, float* __restrict__ el, float* __restrict__ er)
{
    const int t = threadIdx.x;
    const int b = blockIdx.x >> 7;            // 128 n-tiles per batch
    const int n0 = (blockIdx.x & 127) * 16;

    __shared__ __align__(16) float xs[16][F_IN];   // 8 KB
    {
        const f32x4* src = (const f32x4*)(x + ((size_t)b * NN + n0) * F_IN);
        f32x4* dst = (f32x4*)&xs[0][0];
        dst[t] = src[t];
        dst[t + 256] = src[t + 256];
    }
    __syncthreads();

    float acc[16];
#pragma unroll
    for (int n = 0; n < 16; ++n) acc[n] = 0.f;

    const float* wrow = W + (size_t)t * F_IN;
#pragma unroll 2
    for (int k0 = 0; k0 < F_IN; k0 += 8) {
        f32x4 w0 = *(const f32x4*)(wrow + k0);
        f32x4 w1 = *(const f32x4*)(wrow + k0 + 4);
#pragma unroll
        for (int n = 0; n < 16; ++n) {
            f32x4 xa = *(const f32x4*)&xs[n][k0];       // wave-uniform: LDS broadcast
            f32x4 xb = *(const f32x4*)&xs[n][k0 + 4];
            float s = acc[n];
            s = fmaf(xa[0], w0[0], s); s = fmaf(xa[1], w0[1], s);
            s = fmaf(xa[2], w0[2], s); s = fmaf(xa[3], w0[3], s);
            s = fmaf(xb[0], w1[0], s); s = fmaf(xb[1], w1[1], s);
            s = fmaf(xb[2], w1[2], s); s = fmaf(xb[3], w1[3], s);
            acc[n] = s;
        }
    }

    // e_l / e_r: wave w covers head w's 64 dims; butterfly over lanes.
    const int w = t >> 6, lane = t & 63;
    const float al = a_l[t];
    const float ar = a_r[t];
    float my_el = 0.f, my_er = 0.f;
#pragma unroll
    for (int n = 0; n < 16; ++n) {
        float vl = acc[n] * al;
        float vr = acc[n] * ar;
#pragma unroll
        for (int off = 32; off; off >>= 1) {
            vl += __shfl_xor(vl, off, 64);
            vr += __shfl_xor(vr, off, 64);
        }
        if (lane == n) { my_el = vl; my_er = vr; }
    }
    if (lane < 16) {
        el[((size_t)b * NH + w) * NN + n0 + lane] = my_el;
        er[((size_t)b * NH + w) * NN + n0 + lane] = my_er;
    }

    u16* hrow = hT + ((size_t)b * F_OUT + t) * NN + n0;
    s16x8 pk0, pk1;
#pragma unroll
    for (int n = 0; n < 8; ++n) pk0[n] = (short)f32_to_bf16_rtn(acc[n]);
#pragma unroll
    for (int n = 0; n < 8; ++n) pk1[n] = (short)f32_to_bf16_rtn(acc[n + 8]);
    *(s16x8*)hrow = pk0;
    *(s16x8*)(hrow + 8) = pk1;
}

// K2: fused masked softmax + aggregation.
// Block = (b, 32-row i-tile), 16 waves = (kk jhalf-of-64tile, rh, head).
// hT tile staged to LDS via global_load_lds (XOR-swizzled), 4 buffers,
// distance-2 prefetch, counted vmcnt(8); adj/e_r distance-1 reg loads.
__global__ __launch_bounds__(1024, 4) void k2_attn(
    const int* __restrict__ adj, const u16* __restrict__ hT,
    const float* __restrict__ el, const float* __restrict__ er,
    float* __restrict__ out)
{
    __shared__ __align__(16) char smem[4 * TILE_B];   // 128 KB
    const int t = threadIdx.x;
    const int wave = t >> 6, l = t & 63;
    const int w = wave & 3;              // head
    const int rh = (wave >> 2) & 1;      // row half of the 32-row tile
    const int kk = wave >> 3;            // k-half of the 64-col tile
    int bid = blockIdx.x;
    bid = (bid & 7) * 32 + (bid >> 3);   // XCD swizzle (256 % 8 == 0, bijective)
    const int b = bid >> 6;
    const int i0 = (bid & 63) * 32;
    const int r = l & 15;                // A row / D col index
    const int kb = l >> 4;               // 0..3: k-slice
    const int ks = kb * 8;
    const int irow = i0 + rh * 16 + r;

    // --- staging source/dest (pre-swizzled source, linear LDS dest) ---
    const u16* hTb = hT + (size_t)b * F_OUT * NN;
    const int glin0 = t, glin1 = t + 1024;
    const int row0 = glin0 >> 3, ci0 = glin0 & 7;
    const int row1 = glin1 >> 3, ci1 = glin1 & 7;
    const char* src0 = (const char*)(hTb + (size_t)row0 * NN) + (ci0 ^ (row0 & 7)) * 16;
    const char* src1 = (const char*)(hTb + (size_t)row1 * NN) + (ci1 ^ (row1 & 7)) * 16;
    const int dst0 = glin0 * 16, dst1 = glin1 * 16;

    // --- swizzled b-frag read offsets (constant over jt) ---
    const int R0 = w * 64 + 0 * 16 + r, R1 = R0 + 16, R2 = R0 + 32, R3 = R0 + 48;
    const int cr = kk * 4 + kb;
    const int rdo0 = R0 * 128 + ((cr ^ (R0 & 7)) * 16);
    const int rdo1 = R1 * 128 + ((cr ^ (R1 & 7)) * 16);
    const int rdo2 = R2 * 128 + ((cr ^ (R2 & 7)) * 16);
    const int rdo3 = R3 * 128 + ((cr ^ (R3 & 7)) * 16);

    const float el_i = el[((size_t)b * NH + w) * NN + irow];
    const int*   adjr = adj + ((size_t)b * NN + irow) * NN + kk * 32 + ks;
    const float* errp = er + ((size_t)b * NH + w) * NN + kk * 32 + ks;

    f32x4 acc0 = {0.f,0.f,0.f,0.f}, acc1 = acc0, acc2 = acc0, acc3 = acc0, accs = acc0;
    s16x8 ones;
#pragma unroll
    for (int k = 0; k < 8; ++k) ones[k] = (short)0x3F80;   // bf16 1.0

    // --- prologue: FIFO order must be L(0), R(0), L(1) ---
    gload16(src0, smem + dst0);
    gload16(src1, smem + dst1);
    __builtin_amdgcn_sched_barrier(0);
    i32x4 a0c = *(const i32x4*)adjr;
    i32x4 a1c = *(const i32x4*)(adjr + 4);
    f32x4 e0c = *(const f32x4*)errp;
    f32x4 e1c = *(const f32x4*)(errp + 4);
    __builtin_amdgcn_sched_barrier(0);
    gload16(src0 + 128, smem + TILE_B + dst0);
    gload16(src1 + 128, smem + TILE_B + dst1);
    __builtin_amdgcn_sched_barrier(0);

    for (int jt = 0; jt < NT; ++jt) {
        // R(jt+1): next adj / e_r into regs (distance 1)
        i32x4 a0n = {0,0,0,0}, a1n = a0n;
        f32x4 e0n = {0.f,0.f,0.f,0.f}, e1n = e0n;
        if (jt < NT - 1) {
            const int* ap = adjr + (jt + 1) * 64;
            const float* ep = errp + (jt + 1) * 64;
            a0n = *(const i32x4*)ap; a1n = *(const i32x4*)(ap + 4);
            e0n = *(const f32x4*)ep; e1n = *(const f32x4*)(ep + 4);
        }
        __builtin_amdgcn_sched_barrier(0);
        // L(jt+2): stage hT tile (distance 2)
        if (jt < NT - 2) {
            char* d = smem + (size_t)((jt + 2) & 3) * TILE_B;
            gload16(src0 + (jt + 2) * 128, d + dst0);
            gload16(src1 + (jt + 2) * 128, d + dst1);
        }
        __builtin_amdgcn_sched_barrier(0);
        // counted wait: L(jt) and R(jt) retired; 8 newer ops may stay in flight
        if (jt < NT - 2)      asm volatile("s_waitcnt vmcnt(8)" ::: "memory");
        else if (jt == NT - 2) asm volatile("s_waitcnt vmcnt(6)" ::: "memory");
        else                   asm volatile("s_waitcnt vmcnt(0)" ::: "memory");
        __builtin_amdgcn_s_barrier();

        const char* bp = smem + (size_t)(jt & 3) * TILE_B;
        s16x8 b0 = *(const s16x8*)(bp + rdo0);
        s16x8 b1 = *(const s16x8*)(bp + rdo1);
        s16x8 b2 = *(const s16x8*)(bp + rdo2);
        s16x8 b3 = *(const s16x8*)(bp + rdo3);

        // P-gen: 8 scores -> masked exp -> bf16(trunc) packed via v_perm
        uint32_t pu[8];
#pragma unroll
        for (int k = 0; k < 8; ++k) {
            float e_j = (k < 4) ? e0c[k] : e1c[k - 4];
            int   av  = (k < 4) ? a0c[k] : a1c[k - 4];
            float s = el_i + e_j;
            s = fmaxf(s, 0.2f * s);          // leaky_relu(0.2)
            float pe = __expf(s);
            pe = av ? pe : 0.f;              // adjacency mask
            union { float f; uint32_t u; } cv; cv.f = pe;
            pu[k] = cv.u;
        }
        union { s16x8 v; uint32_t u[4]; } af;
        af.u[0] = __builtin_amdgcn_perm(pu[1], pu[0], 0x07060302);
        af.u[1] = __builtin_amdgcn_perm(pu[3], pu[2], 0x07060302);
        af.u[2] = __builtin_amdgcn_perm(pu[5], pu[4], 0x07060302);
        af.u[3] = __builtin_amdgcn_perm(pu[7], pu[6], 0x07060302);

        acc0 = __builtin_amdgcn_mfma_f32_16x16x32_bf16(af.v, b0, acc0, 0, 0, 0);
        acc1 = __builtin_amdgcn_mfma_f32_16x16x32_bf16(af.v, b1, acc1, 0, 0, 0);
        acc2 = __builtin_amdgcn_mfma_f32_16x16x32_bf16(af.v, b2, acc2, 0, 0, 0);
        acc3 = __builtin_amdgcn_mfma_f32_16x16x32_bf16(af.v, b3, acc3, 0, 0, 0);
        accs = __builtin_amdgcn_mfma_f32_16x16x32_bf16(af.v, ones, accs, 0, 0, 0);

        if (jt < NT - 1) { a0c = a0n; a1c = a1n; e0c = e0n; e1c = e1n; }
    }

    // --- epilogue: cross-kk reduce through LDS (aliases stage buffers) ---
    asm volatile("s_waitcnt lgkmcnt(0)" ::: "memory");
    __builtin_amdgcn_s_barrier();    // everyone done reading stage buffers

    float* racc = (float*)smem;      // [8 wavepairs][64 lanes][20]
    if (kk == 1) {
        float* p = racc + ((size_t)(wave - 8) * 64 + l) * 20;
        *(f32x4*)(p +  0) = acc0; *(f32x4*)(p +  4) = acc1;
        *(f32x4*)(p +  8) = acc2; *(f32x4*)(p + 12) = acc3;
        *(f32x4*)(p + 16) = accs;
    }
    __syncthreads();
    if (kk == 0) {
        const float* p = racc + ((size_t)wave * 64 + l) * 20;
        acc0 += *(const f32x4*)(p +  0); acc1 += *(const f32x4*)(p +  4);
        acc2 += *(const f32x4*)(p +  8); acc3 += *(const f32x4*)(p + 12);
        accs += *(const f32x4*)(p + 16);

        float* op = out + ((size_t)b * NN + i0 + rh * 16) * F_OUT + w * HD;
#pragma unroll
        for (int q = 0; q < 4; ++q) {
            const int row = kb * 4 + q;          // D row for acc[q]
            float inv = 1.0f / accs[q];          // rowsum via ones-MFMA
            op[(size_t)row * F_OUT +  0 + r] = acc0[q] * inv;
            op[(size_t)row * F_OUT + 16 + r] = acc1[q] * inv;
            op[(size_t)row * F_OUT + 32 + r] = acc2[q] * inv;
            op[(size_t)row * F_OUT + 48 + r] = acc3[q] * inv;
        }
    }
}

extern "C" void kernel_launch(void* const* d_in, const int* in_sizes, int n_in,
                              void* d_out, int out_size, void* d_ws, size_t ws_size,
                              hipStream_t stream) {
    const float* x   = (const float*)d_in[0];
    const int*   adj = (const int*)d_in[1];
    const float* W   = (const float*)d_in[2];
    const float* a_l = (const float*)d_in[3];
    const float* a_r = (const float*)d_in[4];
    float* out = (float*)d_out;

    u16*   hT = (u16*)d_ws;
    float* el = (float*)((char*)d_ws + (size_t)BB * F_OUT * NN * sizeof(u16));
    float* er = el + (size_t)BB * NH * NN;

    k1_proj<<<BB * (NN / 16), 256, 0, stream>>>(x, W, a_l, a_r, hT, el, er);
    k2_attn<<<BB * (NN / 32), 1024, 0, stream>>>(adj, hT, el, er, out);
}

// Round 4
// 75.019 us; speedup vs baseline: 1.6196x; 1.1590x over previous
//
#include <hip/hip_runtime.h>
#include <stdint.h>

#define BB 4
#define NN 2048
#define F_IN 128
#define F_OUT 256
#define NH 4
#define HD 64
#define NT 32            // 32 j-tiles of 64 columns
#define TILE_B 32768     // staged hT tile: 256 rows x 128 B

typedef float f32x4 __attribute__((ext_vector_type(4)));
typedef short s16x8 __attribute__((ext_vector_type(8)));
typedef unsigned long long u64;
typedef unsigned short u16;

#define LOG2E 1.4426950408889634f

__device__ __forceinline__ u16 f32_to_bf16_rtn(float f) {
    union { float f; uint32_t u; } v; v.f = f;
    uint32_t u = v.u;
    u += 0x7fffu + ((u >> 16) & 1u);
    return (u16)(u >> 16);
}

__device__ __forceinline__ float exp2_fast(float x) {
#if __has_builtin(__builtin_amdgcn_exp2f)
    return __builtin_amdgcn_exp2f(x);
#else
    return exp2f(x);
#endif
}

__device__ __forceinline__ void gload16(const void* g, void* l) {
    __builtin_amdgcn_global_load_lds(
        (const __attribute__((address_space(1))) unsigned int*)g,
        (__attribute__((address_space(3))) unsigned int*)l, 16, 0, 0);
}

// K0: pack adj int32 -> bitmask u64[B*N][32]. One wave per row, ballot per 64 j.
__global__ __launch_bounds__(256) void k0_pack(
    const int* __restrict__ adj, u64* __restrict__ abits)
{
    const int wid = (blockIdx.x << 2) | (threadIdx.x >> 6);   // row id
    const int lane = threadIdx.x & 63;
    const int* rowp = adj + (size_t)wid * NN;
    u64 mym = 0;
#pragma unroll 8
    for (int jt = 0; jt < 32; ++jt) {
        int v = rowp[jt * 64 + lane];
        u64 m = __ballot(v != 0);
        if (lane == jt) mym = m;
    }
    if (lane < 32) abits[(size_t)wid * 32 + lane] = mym;
}

// K1: h = x @ W^T (fp32). 16-row n-tiles, 512 blocks.
// el/er stored pre-scaled by log2(e) so K2 uses raw v_exp_f32.
__global__ __launch_bounds__(256, 2) void k1_proj(
    const float* __restrict__ x, const float* __restrict__ W,
    const float* __restrict__ a_l, const float* __restrict__ a_r,
    u16* __restrict__ hT, float* __restrict__ el, float* __restrict__ er)
{
    const int t = threadIdx.x;
    const int b = blockIdx.x >> 7;
    const int n0 = (blockIdx.x & 127) * 16;

    __shared__ __align__(16) float xs[16][F_IN];   // 8 KB
    {
        const f32x4* src = (const f32x4*)(x + ((size_t)b * NN + n0) * F_IN);
        f32x4* dst = (f32x4*)&xs[0][0];
        dst[t] = src[t];
        dst[t + 256] = src[t + 256];
    }
    __syncthreads();

    float acc[16];
#pragma unroll
    for (int n = 0; n < 16; ++n) acc[n] = 0.f;

    const float* wrow = W + (size_t)t * F_IN;
#pragma unroll 2
    for (int k0 = 0; k0 < F_IN; k0 += 8) {
        f32x4 w0 = *(const f32x4*)(wrow + k0);
        f32x4 w1 = *(const f32x4*)(wrow + k0 + 4);
#pragma unroll
        for (int n = 0; n < 16; ++n) {
            f32x4 xa = *(const f32x4*)&xs[n][k0];
            f32x4 xb = *(const f32x4*)&xs[n][k0 + 4];
            float s = acc[n];
            s = fmaf(xa[0], w0[0], s); s = fmaf(xa[1], w0[1], s);
            s = fmaf(xa[2], w0[2], s); s = fmaf(xa[3], w0[3], s);
            s = fmaf(xb[0], w1[0], s); s = fmaf(xb[1], w1[1], s);
            s = fmaf(xb[2], w1[2], s); s = fmaf(xb[3], w1[3], s);
            acc[n] = s;
        }
    }

    const int w = t >> 6, lane = t & 63;
    const float al = a_l[t];
    const float ar = a_r[t];
    float my_el = 0.f, my_er = 0.f;
#pragma unroll
    for (int n = 0; n < 16; ++n) {
        float vl = acc[n] * al;
        float vr = acc[n] * ar;
#pragma unroll
        for (int off = 32; off; off >>= 1) {
            vl += __shfl_xor(vl, off, 64);
            vr += __shfl_xor(vr, off, 64);
        }
        if (lane == n) { my_el = vl; my_er = vr; }
    }
    if (lane < 16) {
        el[((size_t)b * NH + w) * NN + n0 + lane] = my_el * LOG2E;
        er[((size_t)b * NH + w) * NN + n0 + lane] = my_er * LOG2E;
    }

    u16* hrow = hT + ((size_t)b * F_OUT + t) * NN + n0;
    s16x8 pk0, pk1;
#pragma unroll
    for (int n = 0; n < 8; ++n) pk0[n] = (short)f32_to_bf16_rtn(acc[n]);
#pragma unroll
    for (int n = 0; n < 8; ++n) pk1[n] = (short)f32_to_bf16_rtn(acc[n + 8]);
    *(s16x8*)hrow = pk0;
    *(s16x8*)(hrow + 8) = pk1;
}

// K2: fused masked softmax + aggregation. Adjacency from bitmasks (regs),
// hT tile staged to LDS via global_load_lds (swizzled), 4 buffers, dist-2,
// counted vmcnt(7); e_r + bitmask word at dist-1 in registers.
__global__ __launch_bounds__(1024, 4) void k2_attn(
    const u64* __restrict__ abits, const u16* __restrict__ hT,
    const float* __restrict__ el, const float* __restrict__ er,
    float* __restrict__ out)
{
    __shared__ __align__(16) char smem[4 * TILE_B];   // 128 KB
    const int t = threadIdx.x;
    const int wave = t >> 6, l = t & 63;
    const int w = wave & 3;
    const int rh = (wave >> 2) & 1;
    const int kk = wave >> 3;
    int bid = blockIdx.x;
    bid = (bid & 7) * 32 + (bid >> 3);   // XCD swizzle (256 % 8 == 0)
    const int b = bid >> 6;
    const int i0 = (bid & 63) * 32;
    const int r = l & 15;
    const int kb = l >> 4;
    const int ks = kb * 8;
    const int irow = i0 + rh * 16 + r;
    const int shiftv = (kk * 4 + kb) * 8;      // byte position in u64 word

    // staging source/dest (pre-swizzled source, linear LDS dest)
    const u16* hTb = hT + (size_t)b * F_OUT * NN;
    const int glin0 = t, glin1 = t + 1024;
    const int row0 = glin0 >> 3, ci0 = glin0 & 7;
    const int row1 = glin1 >> 3, ci1 = glin1 & 7;
    const char* src0 = (const char*)(hTb + (size_t)row0 * NN) + (ci0 ^ (row0 & 7)) * 16;
    const char* src1 = (const char*)(hTb + (size_t)row1 * NN) + (ci1 ^ (row1 & 7)) * 16;
    const int dst0 = glin0 * 16, dst1 = glin1 * 16;

    // swizzled b-frag read offsets
    const int R0 = w * 64 + r, R1 = R0 + 16, R2 = R0 + 32, R3 = R0 + 48;
    const int cr = kk * 4 + kb;
    const int rdo0 = R0 * 128 + ((cr ^ (R0 & 7)) * 16);
    const int rdo1 = R1 * 128 + ((cr ^ (R1 & 7)) * 16);
    const int rdo2 = R2 * 128 + ((cr ^ (R2 & 7)) * 16);
    const int rdo3 = R3 * 128 + ((cr ^ (R3 & 7)) * 16);

    const float* errp = er + ((size_t)b * NH + w) * NN + kk * 32 + ks;
    const u64*   mrow = abits + ((size_t)b * NN + irow) * 32;

    f32x4 acc0 = {0.f,0.f,0.f,0.f}, acc1 = acc0, acc2 = acc0, acc3 = acc0, accs = acc0;
    s16x8 ones;
#pragma unroll
    for (int k = 0; k < 8; ++k) ones[k] = (short)0x3F80;

    // prologue (FIFO: el_i, R(0), L(0), L(1))
    const float el_i = el[((size_t)b * NH + w) * NN + irow];
    __builtin_amdgcn_sched_barrier(0);
    f32x4 e0c = *(const f32x4*)errp;
    f32x4 e1c = *(const f32x4*)(errp + 4);
    u64   mc  = mrow[0];
    __builtin_amdgcn_sched_barrier(0);
    gload16(src0, smem + dst0);
    gload16(src1, smem + dst1);
    __builtin_amdgcn_sched_barrier(0);
    gload16(src0 + 128, smem + TILE_B + dst0);
    gload16(src1 + 128, smem + TILE_B + dst1);
    __builtin_amdgcn_sched_barrier(0);

#define COMPUTE(JT, E0, E1, MM)                                              \
    {                                                                        \
        const char* bp = smem + (size_t)((JT) & 3) * TILE_B;                 \
        s16x8 b0 = *(const s16x8*)(bp + rdo0);                               \
        s16x8 b1 = *(const s16x8*)(bp + rdo1);                               \
        s16x8 b2 = *(const s16x8*)(bp + rdo2);                               \
        s16x8 b3 = *(const s16x8*)(bp + rdo3);                               \
        uint32_t w2 = (uint32_t)((MM) >> shiftv);                            \
        uint32_t pu[8];                                                      \
        _Pragma("unroll")                                                    \
        for (int k = 0; k < 8; ++k) {                                        \
            float e_j = (k < 4) ? (E0)[k] : (E1)[k - 4];                     \
            float s = el_i + e_j;                                            \
            s = fmaxf(s, 0.2f * s);                                          \
            float pe = exp2_fast(s);                                         \
            int32_t msk = ((int32_t)(w2 << (31 - k))) >> 31;                 \
            union { float f; uint32_t u; } cv; cv.f = pe;                    \
            pu[k] = cv.u & (uint32_t)msk;                                    \
        }                                                                    \
        union { s16x8 v; uint32_t u[4]; } af;                                \
        af.u[0] = __builtin_amdgcn_perm(pu[1], pu[0], 0x07060302);           \
        af.u[1] = __builtin_amdgcn_perm(pu[3], pu[2], 0x07060302);           \
        af.u[2] = __builtin_amdgcn_perm(pu[5], pu[4], 0x07060302);           \
        af.u[3] = __builtin_amdgcn_perm(pu[7], pu[6], 0x07060302);           \
        acc0 = __builtin_amdgcn_mfma_f32_16x16x32_bf16(af.v, b0, acc0, 0, 0, 0); \
        acc1 = __builtin_amdgcn_mfma_f32_16x16x32_bf16(af.v, b1, acc1, 0, 0, 0); \
        acc2 = __builtin_amdgcn_mfma_f32_16x16x32_bf16(af.v, b2, acc2, 0, 0, 0); \
        acc3 = __builtin_amdgcn_mfma_f32_16x16x32_bf16(af.v, ones, accs, 0, 0, 0), \
        accs = acc3, acc3 = __builtin_amdgcn_mfma_f32_16x16x32_bf16(af.v, b3, \
            *(f32x4*)&acc3, 0, 0, 0);                                        \
    }

#undef COMPUTE
#define COMPUTE(JT, E0, E1, MM)                                              \
    {                                                                        \
        const char* bp = smem + (size_t)((JT) & 3) * TILE_B;                 \
        s16x8 b0 = *(const s16x8*)(bp + rdo0);                               \
        s16x8 b1 = *(const s16x8*)(bp + rdo1);                               \
        s16x8 b2 = *(const s16x8*)(bp + rdo2);                               \
        s16x8 b3 = *(const s16x8*)(bp + rdo3);                               \
        uint32_t w2 = (uint32_t)((MM) >> shiftv);                            \
        uint32_t pu[8];                                                      \
        _Pragma("unroll")                                                    \
        for (int k = 0; k < 8; ++k) {                                        \
            float e_j = (k < 4) ? (E0)[k] : (E1)[k - 4];                     \
            float s = el_i + e_j;                                            \
            s = fmaxf(s, 0.2f * s);                                          \
            float pe = exp2_fast(s);                                         \
            int32_t msk = ((int32_t)(w2 << (31 - k))) >> 31;                 \
            union { float f; uint32_t u; } cv; cv.f = pe;                    \
            pu[k] = cv.u & (uint32_t)msk;                                    \
        }                                                                    \
        union { s16x8 v; uint32_t u[4]; } af;                                \
        af.u[0] = __builtin_amdgcn_perm(pu[1], pu[0], 0x07060302);           \
        af.u[1] = __builtin_amdgcn_perm(pu[3], pu[2], 0x07060302);           \
        af.u[2] = __builtin_amdgcn_perm(pu[5], pu[4], 0x07060302);           \
        af.u[3] = __builtin_amdgcn_perm(pu[7], pu[6], 0x07060302);           \
        acc0 = __builtin_amdgcn_mfma_f32_16x16x32_bf16(af.v, b0, acc0, 0, 0, 0); \
        acc1 = __builtin_amdgcn_mfma_f32_16x16x32_bf16(af.v, b1, acc1, 0, 0, 0); \
        acc2 = __builtin_amdgcn_mfma_f32_16x16x32_bf16(af.v, b2, acc2, 0, 0, 0); \
        acc3 = __builtin_amdgcn_mfma_f32_16x16x32_bf16(af.v, b3, acc3, 0, 0, 0); \
        accs = __builtin_amdgcn_mfma_f32_16x16x32_bf16(af.v, ones, accs, 0, 0, 0); \
    }

    // main loop: bodies 0..NT-3 (R dist-1, L dist-2, vmcnt(7))
#pragma unroll 2
    for (int jt = 0; jt < NT - 2; ++jt) {
        const float* ep = errp + (jt + 1) * 64;
        f32x4 e0n = *(const f32x4*)ep;
        f32x4 e1n = *(const f32x4*)(ep + 4);
        u64   mn  = mrow[jt + 1];
        __builtin_amdgcn_sched_barrier(0);
        {
            char* d = smem + (size_t)((jt + 2) & 3) * TILE_B;
            gload16(src0 + (jt + 2) * 128, d + dst0);
            gload16(src1 + (jt + 2) * 128, d + dst1);
        }
        __builtin_amdgcn_sched_barrier(0);
        asm volatile("s_waitcnt vmcnt(7)" ::: "memory");
        __builtin_amdgcn_s_barrier();
        COMPUTE(jt, e0c, e1c, mc);
        e0c = e0n; e1c = e1n; mc = mn;
    }
    // body NT-2: issue R(NT-1) only, vmcnt(5)
    {
        const float* ep = errp + (NT - 1) * 64;
        f32x4 e0n = *(const f32x4*)ep;
        f32x4 e1n = *(const f32x4*)(ep + 4);
        u64   mn  = mrow[NT - 1];
        __builtin_amdgcn_sched_barrier(0);
        asm volatile("s_waitcnt vmcnt(5)" ::: "memory");
        __builtin_amdgcn_s_barrier();
        COMPUTE(NT - 2, e0c, e1c, mc);
        e0c = e0n; e1c = e1n; mc = mn;
    }
    // body NT-1: vmcnt(0)
    {
        asm volatile("s_waitcnt vmcnt(0)" ::: "memory");
        __builtin_amdgcn_s_barrier();
        COMPUTE(NT - 1, e0c, e1c, mc);
    }

    // epilogue: cross-kk reduce through LDS (aliases stage buffers)
    asm volatile("s_waitcnt lgkmcnt(0)" ::: "memory");
    __builtin_amdgcn_s_barrier();

    float* racc = (float*)smem;      // [8 wavepairs][64 lanes][20]
    if (kk == 1) {
        float* p = racc + ((size_t)(wave - 8) * 64 + l) * 20;
        *(f32x4*)(p +  0) = acc0; *(f32x4*)(p +  4) = acc1;
        *(f32x4*)(p +  8) = acc2; *(f32x4*)(p + 12) = acc3;
        *(f32x4*)(p + 16) = accs;
    }
    __syncthreads();
    if (kk == 0) {
        const float* p = racc + ((size_t)wave * 64 + l) * 20;
        acc0 += *(const f32x4*)(p +  0); acc1 += *(const f32x4*)(p +  4);
        acc2 += *(const f32x4*)(p +  8); acc3 += *(const f32x4*)(p + 12);
        accs += *(const f32x4*)(p + 16);

        float* op = out + ((size_t)b * NN + i0 + rh * 16) * F_OUT + w * HD;
#pragma unroll
        for (int q = 0; q < 4; ++q) {
            const int row = kb * 4 + q;
            float inv = 1.0f / accs[q];
            op[(size_t)row * F_OUT +  0 + r] = acc0[q] * inv;
            op[(size_t)row * F_OUT + 16 + r] = acc1[q] * inv;
            op[(size_t)row * F_OUT + 32 + r] = acc2[q] * inv;
            op[(size_t)row * F_OUT + 48 + r] = acc3[q] * inv;
        }
    }
}

extern "C" void kernel_launch(void* const* d_in, const int* in_sizes, int n_in,
                              void* d_out, int out_size, void* d_ws, size_t ws_size,
                              hipStream_t stream) {
    const float* x   = (const float*)d_in[0];
    const int*   adj = (const int*)d_in[1];
    const float* W   = (const float*)d_in[2];
    const float* a_l = (const float*)d_in[3];
    const float* a_r = (const float*)d_in[4];
    float* out = (float*)d_out;

    char* ws = (char*)d_ws;
    u16*   hT    = (u16*)ws;                                   // 4 MB
    u64*   abits = (u64*)(ws + (size_t)BB * F_OUT * NN * 2);   // 2 MB
    float* el    = (float*)(ws + (size_t)BB * F_OUT * NN * 2 + (size_t)BB * NN * 32 * 8);
    float* er    = el + (size_t)BB * NH * NN;

    k0_pack<<<BB * NN / 4, 256, 0, stream>>>(adj, abits);
    k1_proj<<<BB * (NN / 16), 256, 0, stream>>>(x, W, a_l, a_r, hT, el, er);
    k2_attn<<<BB * (NN / 32), 1024, 0, stream>>>(abits, hT, el, er, out);
}

// Round 5
// 65.591 us; speedup vs baseline: 1.8523x; 1.1437x over previous
//
#include <hip/hip_runtime.h>
#include <stdint.h>

#define BB 4
#define NN 2048
#define F_IN 128
#define F_OUT 256
#define NH 4
#define HD 64
#define NT 32            // 32 j-tiles of 64 columns
#define TILE_B 32768     // staged hT tile: 256 rows x 128 B

typedef float f32x4 __attribute__((ext_vector_type(4)));
typedef short s16x8 __attribute__((ext_vector_type(8)));
typedef unsigned long long u64;
typedef unsigned short u16;

#define LOG2E 1.4426950408889634f

__device__ __forceinline__ u16 f32_to_bf16_rtn(float f) {
    union { float f; uint32_t u; } v; v.f = f;
    uint32_t u = v.u;
    u += 0x7fffu + ((u >> 16) & 1u);
    return (u16)(u >> 16);
}

__device__ __forceinline__ float exp2_fast(float x) {
#if __has_builtin(__builtin_amdgcn_exp2f)
    return __builtin_amdgcn_exp2f(x);
#else
    return exp2f(x);
#endif
}

__device__ __forceinline__ int sbfe1(uint32_t v, int k) {
#if __has_builtin(__builtin_amdgcn_sbfe)
    return __builtin_amdgcn_sbfe((int)v, k, 1);   // bit k sign-extended: 0 or -1
#else
    return ((int32_t)(v << (31 - k))) >> 31;
#endif
}

__device__ __forceinline__ void gload16(const void* g, void* l) {
    __builtin_amdgcn_global_load_lds(
        (const __attribute__((address_space(1))) unsigned int*)g,
        (__attribute__((address_space(3))) unsigned int*)l, 16, 0, 0);
}

// K01: fused adj-pack (HBM-streaming) + projection (VALU/LDS) — complementary
// pipes overlap. Blocks 0..511 = proj (16-row tiles); 512..2559 = pack.
__global__ __launch_bounds__(256) void k01(
    const int* __restrict__ adj, const float* __restrict__ x,
    const float* __restrict__ W, const float* __restrict__ a_l,
    const float* __restrict__ a_r, u64* __restrict__ abits,
    u16* __restrict__ hT, float* __restrict__ el, float* __restrict__ er)
{
    const int t = threadIdx.x;

    if (blockIdx.x >= 512) {
        // ---- pack adj int32 -> bitmask u64[B*N][32], one wave per row ----
        const int wid = ((blockIdx.x - 512) << 2) | (t >> 6);
        const int lane = t & 63;
        const int* rowp = adj + (size_t)wid * NN;
        u64 mym = 0;
#pragma unroll 8
        for (int jt = 0; jt < 32; ++jt) {
            int v = rowp[jt * 64 + lane];
            u64 m = __ballot(v != 0);
            if (lane == jt) mym = m;
        }
        if (lane < 32) abits[(size_t)wid * 32 + lane] = mym;
        return;
    }

    // ---- projection: h = x @ W^T (fp32), hT bf16 [B,F_OUT,N], el/er ----
    const int b = blockIdx.x >> 7;
    const int n0 = (blockIdx.x & 127) * 16;

    __shared__ __align__(16) float xs[16][F_IN];   // 8 KB
    {
        const f32x4* src = (const f32x4*)(x + ((size_t)b * NN + n0) * F_IN);
        f32x4* dst = (f32x4*)&xs[0][0];
        dst[t] = src[t];
        dst[t + 256] = src[t + 256];
    }
    __syncthreads();

    float acc[16];
#pragma unroll
    for (int n = 0; n < 16; ++n) acc[n] = 0.f;

    const float* wrow = W + (size_t)t * F_IN;
#pragma unroll 2
    for (int k0 = 0; k0 < F_IN; k0 += 8) {
        f32x4 w0 = *(const f32x4*)(wrow + k0);
        f32x4 w1 = *(const f32x4*)(wrow + k0 + 4);
#pragma unroll
        for (int n = 0; n < 16; ++n) {
            f32x4 xa = *(const f32x4*)&xs[n][k0];
            f32x4 xb = *(const f32x4*)&xs[n][k0 + 4];
            float s = acc[n];
            s = fmaf(xa[0], w0[0], s); s = fmaf(xa[1], w0[1], s);
            s = fmaf(xa[2], w0[2], s); s = fmaf(xa[3], w0[3], s);
            s = fmaf(xb[0], w1[0], s); s = fmaf(xb[1], w1[1], s);
            s = fmaf(xb[2], w1[2], s); s = fmaf(xb[3], w1[3], s);
            acc[n] = s;
        }
    }

    const int w = t >> 6, lane = t & 63;
    const float al = a_l[t];
    const float ar = a_r[t];
    float my_el = 0.f, my_er = 0.f;
#pragma unroll
    for (int n = 0; n < 16; ++n) {
        float vl = acc[n] * al;
        float vr = acc[n] * ar;
#pragma unroll
        for (int off = 32; off; off >>= 1) {
            vl += __shfl_xor(vl, off, 64);
            vr += __shfl_xor(vr, off, 64);
        }
        if (lane == n) { my_el = vl; my_er = vr; }
    }
    if (lane < 16) {
        el[((size_t)b * NH + w) * NN + n0 + lane] = my_el * LOG2E;
        er[((size_t)b * NH + w) * NN + n0 + lane] = my_er * LOG2E;
    }

    u16* hrow = hT + ((size_t)b * F_OUT + t) * NN + n0;
    s16x8 pk0, pk1;
#pragma unroll
    for (int n = 0; n < 8; ++n) pk0[n] = (short)f32_to_bf16_rtn(acc[n]);
#pragma unroll
    for (int n = 0; n < 8; ++n) pk1[n] = (short)f32_to_bf16_rtn(acc[n + 8]);
    *(s16x8*)hrow = pk0;
    *(s16x8*)(hrow + 8) = pk1;
}

// K2: fused masked softmax + aggregation, 8 waves = (head w, j-half jh).
// Each wave carries BOTH 16-row halves (2 A-frags) -> B-frag reads are
// deduplicated: 32 ds_read_b128 per block-iter == staged volume.
// 4 stage buffers, L at dist-2, R (e_r + 2 mask words) at dist-1, vmcnt(12).
__global__ __launch_bounds__(512, 2) void k2_attn(
    const u64* __restrict__ abits, const u16* __restrict__ hT,
    const float* __restrict__ el, const float* __restrict__ er,
    float* __restrict__ out)
{
    __shared__ __align__(16) char smem[4 * TILE_B];   // 128 KB
    const int t = threadIdx.x;
    const int wave = t >> 6, l = t & 63;
    const int w = wave & 3;              // head
    const int jh = wave >> 2;            // j-half of the 64-col tile
    int bid = blockIdx.x;
    bid = (bid & 7) * 32 + (bid >> 3);   // XCD swizzle (256 % 8 == 0)
    const int b = bid >> 6;
    const int i0 = (bid & 63) * 32;
    const int r = l & 15;                // A row / D col index
    const int kb = l >> 4;               // k-slice 0..3
    const int ks = kb * 8;
    const int irow0 = i0 + r;
    const int irow1 = i0 + 16 + r;
    const int shiftv = jh * 32 + ks;     // bit base within the u64 mask word

    // staging source/dest (pre-swizzled source, linear LDS dest); 4 segs/thread
    const u16* hTb = hT + (size_t)b * F_OUT * NN;
    const char* srcp[4];
    int dstp[4];
#pragma unroll
    for (int p = 0; p < 4; ++p) {
        const int glin = t + p * 512;
        const int row = glin >> 3, ci = glin & 7;
        srcp[p] = (const char*)(hTb + (size_t)row * NN) + (ci ^ (row & 7)) * 16;
        dstp[p] = glin * 16;
    }

    // swizzled b-frag read offsets (constant over jt)
    const int R0 = w * 64 + r, R1 = R0 + 16, R2 = R0 + 32, R3 = R0 + 48;
    const int cr = jh * 4 + kb;
    const int rdo0 = R0 * 128 + ((cr ^ (R0 & 7)) * 16);
    const int rdo1 = R1 * 128 + ((cr ^ (R1 & 7)) * 16);
    const int rdo2 = R2 * 128 + ((cr ^ (R2 & 7)) * 16);
    const int rdo3 = R3 * 128 + ((cr ^ (R3 & 7)) * 16);

    const float* errp = er + ((size_t)b * NH + w) * NN + jh * 32 + ks;
    const u64*   mr0  = abits + ((size_t)b * NN + irow0) * 32;
    const u64*   mr1  = abits + ((size_t)b * NN + irow1) * 32;

    f32x4 a00 = {0.f,0.f,0.f,0.f}, a01 = a00, a02 = a00, a03 = a00, as0 = a00;
    f32x4 a10 = a00, a11 = a00, a12 = a00, a13 = a00, as1 = a00;
    s16x8 ones;
#pragma unroll
    for (int k = 0; k < 8; ++k) ones[k] = (short)0x3F80;   // bf16 1.0

    // prologue (FIFO: el(2), R(0)=4, L(0)=4, L(1)=4)
    const float el_i0 = el[((size_t)b * NH + w) * NN + irow0];
    const float el_i1 = el[((size_t)b * NH + w) * NN + irow1];
    __builtin_amdgcn_sched_barrier(0);
    f32x4 e0c = *(const f32x4*)errp;
    f32x4 e1c = *(const f32x4*)(errp + 4);
    u64   mc0 = mr0[0];
    u64   mc1 = mr1[0];
    __builtin_amdgcn_sched_barrier(0);
#pragma unroll
    for (int p = 0; p < 4; ++p) gload16(srcp[p], smem + dstp[p]);
    __builtin_amdgcn_sched_barrier(0);
#pragma unroll
    for (int p = 0; p < 4; ++p) gload16(srcp[p] + 128, smem + TILE_B + dstp[p]);
    __builtin_amdgcn_sched_barrier(0);

#define MFMA_BF16 __builtin_amdgcn_mfma_f32_16x16x32_bf16
#define COMPUTE(JT)                                                          \
    {                                                                        \
        const char* bp = smem + (size_t)((JT) & 3) * TILE_B;                 \
        s16x8 b0 = *(const s16x8*)(bp + rdo0);                               \
        s16x8 b1 = *(const s16x8*)(bp + rdo1);                               \
        s16x8 b2 = *(const s16x8*)(bp + rdo2);                               \
        s16x8 b3 = *(const s16x8*)(bp + rdo3);                               \
        uint32_t w2a = (uint32_t)(mc0 >> shiftv);                            \
        uint32_t w2b = (uint32_t)(mc1 >> shiftv);                            \
        uint32_t pua[8], pub[8];                                             \
        _Pragma("unroll")                                                    \
        for (int k = 0; k < 8; ++k) {                                        \
            float e_j = (k < 4) ? e0c[k] : e1c[k - 4];                       \
            float s0 = el_i0 + e_j;                                          \
            float s1 = el_i1 + e_j;                                          \
            s0 = fmaxf(s0, 0.2f * s0);                                       \
            s1 = fmaxf(s1, 0.2f * s1);                                       \
            float p0 = exp2_fast(s0);                                        \
            float p1 = exp2_fast(s1);                                        \
            union { float f; uint32_t u; } c0, c1; c0.f = p0; c1.f = p1;     \
            pua[k] = c0.u & (uint32_t)sbfe1(w2a, k);                         \
            pub[k] = c1.u & (uint32_t)sbfe1(w2b, k);                         \
        }                                                                    \
        union { s16x8 v; uint32_t u[4]; } afa, afb;                          \
        afa.u[0] = __builtin_amdgcn_perm(pua[1], pua[0], 0x07060302);        \
        afa.u[1] = __builtin_amdgcn_perm(pua[3], pua[2], 0x07060302);        \
        afa.u[2] = __builtin_amdgcn_perm(pua[5], pua[4], 0x07060302);        \
        afa.u[3] = __builtin_amdgcn_perm(pua[7], pua[6], 0x07060302);        \
        afb.u[0] = __builtin_amdgcn_perm(pub[1], pub[0], 0x07060302);        \
        afb.u[1] = __builtin_amdgcn_perm(pub[3], pub[2], 0x07060302);        \
        afb.u[2] = __builtin_amdgcn_perm(pub[5], pub[4], 0x07060302);        \
        afb.u[3] = __builtin_amdgcn_perm(pub[7], pub[6], 0x07060302);        \
        a00 = MFMA_BF16(afa.v, b0, a00, 0, 0, 0);                            \
        a01 = MFMA_BF16(afa.v, b1, a01, 0, 0, 0);                            \
        a02 = MFMA_BF16(afa.v, b2, a02, 0, 0, 0);                            \
        a03 = MFMA_BF16(afa.v, b3, a03, 0, 0, 0);                            \
        as0 = MFMA_BF16(afa.v, ones, as0, 0, 0, 0);                          \
        a10 = MFMA_BF16(afb.v, b0, a10, 0, 0, 0);                            \
        a11 = MFMA_BF16(afb.v, b1, a11, 0, 0, 0);                            \
        a12 = MFMA_BF16(afb.v, b2, a12, 0, 0, 0);                            \
        a13 = MFMA_BF16(afb.v, b3, a13, 0, 0, 0);                            \
        as1 = MFMA_BF16(afb.v, ones, as1, 0, 0, 0);                          \
    }

    // main loop: iters 0..NT-3. Steady in-flight at wait point:
    // L(jt+1)4 + R(jt+1)4 + L(jt+2)4 = 12 newest -> vmcnt(12) retires L(jt),R(jt).
#pragma unroll 2
    for (int jt = 0; jt < NT - 2; ++jt) {
        const float* ep = errp + (jt + 1) * 64;
        f32x4 e0n = *(const f32x4*)ep;
        f32x4 e1n = *(const f32x4*)(ep + 4);
        u64   mn0 = mr0[jt + 1];
        u64   mn1 = mr1[jt + 1];
        __builtin_amdgcn_sched_barrier(0);
        {
            char* d = smem + (size_t)((jt + 2) & 3) * TILE_B;
#pragma unroll
            for (int p = 0; p < 4; ++p) gload16(srcp[p] + (jt + 2) * 128, d + dstp[p]);
        }
        __builtin_amdgcn_sched_barrier(0);
        asm volatile("s_waitcnt vmcnt(12)" ::: "memory");
        __builtin_amdgcn_s_barrier();
        COMPUTE(jt);
        e0c = e0n; e1c = e1n; mc0 = mn0; mc1 = mn1;
    }
    // iter NT-2: issue R(NT-1) only; allow R(NT-1)4 + L(NT-1)4 = 8
    {
        const float* ep = errp + (NT - 1) * 64;
        f32x4 e0n = *(const f32x4*)ep;
        f32x4 e1n = *(const f32x4*)(ep + 4);
        u64   mn0 = mr0[NT - 1];
        u64   mn1 = mr1[NT - 1];
        __builtin_amdgcn_sched_barrier(0);
        asm volatile("s_waitcnt vmcnt(8)" ::: "memory");
        __builtin_amdgcn_s_barrier();
        COMPUTE(NT - 2);
        e0c = e0n; e1c = e1n; mc0 = mn0; mc1 = mn1;
    }
    // iter NT-1
    {
        asm volatile("s_waitcnt vmcnt(0)" ::: "memory");
        __builtin_amdgcn_s_barrier();
        COMPUTE(NT - 1);
    }

    // epilogue: cross-jh reduce through LDS (aliases stage buffers)
    asm volatile("s_waitcnt lgkmcnt(0)" ::: "memory");
    __builtin_amdgcn_s_barrier();    // everyone done reading stage buffers

    float* racc = (float*)smem;      // [4 heads][64 lanes][40]
    if (jh == 1) {
        float* p = racc + ((size_t)(wave - 4) * 64 + l) * 40;
        *(f32x4*)(p +  0) = a00; *(f32x4*)(p +  4) = a01;
        *(f32x4*)(p +  8) = a02; *(f32x4*)(p + 12) = a03;
        *(f32x4*)(p + 16) = as0;
        *(f32x4*)(p + 20) = a10; *(f32x4*)(p + 24) = a11;
        *(f32x4*)(p + 28) = a12; *(f32x4*)(p + 32) = a13;
        *(f32x4*)(p + 36) = as1;
    }
    __syncthreads();
    if (jh == 0) {
        const float* p = racc + ((size_t)wave * 64 + l) * 40;
        a00 += *(const f32x4*)(p +  0); a01 += *(const f32x4*)(p +  4);
        a02 += *(const f32x4*)(p +  8); a03 += *(const f32x4*)(p + 12);
        as0 += *(const f32x4*)(p + 16);
        a10 += *(const f32x4*)(p + 20); a11 += *(const f32x4*)(p + 24);
        a12 += *(const f32x4*)(p + 28); a13 += *(const f32x4*)(p + 32);
        as1 += *(const f32x4*)(p + 36);

        float* op = out + ((size_t)b * NN + i0) * F_OUT + w * HD;
#pragma unroll
        for (int q = 0; q < 4; ++q) {
            const int row0 = kb * 4 + q;          // D row for reg q (rh=0)
            float inv0 = 1.0f / as0[q];
            op[(size_t)row0 * F_OUT +  0 + r] = a00[q] * inv0;
            op[(size_t)row0 * F_OUT + 16 + r] = a01[q] * inv0;
            op[(size_t)row0 * F_OUT + 32 + r] = a02[q] * inv0;
            op[(size_t)row0 * F_OUT + 48 + r] = a03[q] * inv0;
            const int row1 = 16 + kb * 4 + q;     // rh=1
            float inv1 = 1.0f / as1[q];
            op[(size_t)row1 * F_OUT +  0 + r] = a10[q] * inv1;
            op[(size_t)row1 * F_OUT + 16 + r] = a11[q] * inv1;
            op[(size_t)row1 * F_OUT + 32 + r] = a12[q] * inv1;
            op[(size_t)row1 * F_OUT + 48 + r] = a13[q] * inv1;
        }
    }
}

extern "C" void kernel_launch(void* const* d_in, const int* in_sizes, int n_in,
                              void* d_out, int out_size, void* d_ws, size_t ws_size,
                              hipStream_t stream) {
    const float* x   = (const float*)d_in[0];
    const int*   adj = (const int*)d_in[1];
    const float* W   = (const float*)d_in[2];
    const float* a_l = (const float*)d_in[3];
    const float* a_r = (const float*)d_in[4];
    float* out = (float*)d_out;

    char* ws = (char*)d_ws;
    u16*   hT    = (u16*)ws;                                   // 4 MB
    u64*   abits = (u64*)(ws + (size_t)BB * F_OUT * NN * 2);   // 2 MB
    float* el    = (float*)(ws + (size_t)BB * F_OUT * NN * 2 + (size_t)BB * NN * 32 * 8);
    float* er    = el + (size_t)BB * NH * NN;

    k01<<<512 + BB * NN / 4, 256, 0, stream>>>(adj, x, W, a_l, a_r, abits, hT, el, er);
    k2_attn<<<BB * (NN / 32), 512, 0, stream>>>(abits, hT, el, er, out);
}

// Round 6
// 56.775 us; speedup vs baseline: 2.1400x; 1.1553x over previous
//
#include <hip/hip_runtime.h>
#include <stdint.h>

#define BB 4
#define NN 2048
#define F_IN 128
#define F_OUT 256
#define NH 4
#define HD 64

typedef float f32x4 __attribute__((ext_vector_type(4)));
typedef short s16x8 __attribute__((ext_vector_type(8)));
typedef unsigned long long u64;
typedef unsigned short u16;

#define LOG2E 1.4426950408889634f

__device__ __forceinline__ u16 f32_to_bf16_rtn(float f) {
    union { float f; uint32_t u; } v; v.f = f;
    uint32_t u = v.u;
    u += 0x7fffu + ((u >> 16) & 1u);
    return (u16)(u >> 16);
}

__device__ __forceinline__ float exp2_fast(float x) {
#if __has_builtin(__builtin_amdgcn_exp2f)
    return __builtin_amdgcn_exp2f(x);
#else
    return exp2f(x);
#endif
}

__device__ __forceinline__ int sbfe1(uint32_t v, int k) {
#if __has_builtin(__builtin_amdgcn_sbfe)
    return __builtin_amdgcn_sbfe((int)v, k, 1);   // bit k sign-extended: 0 or -1
#else
    return ((int32_t)(v << (31 - k))) >> 31;
#endif
}

// K01: fused adj-pack (HBM-streaming) + projection (VALU/LDS) — complementary
// pipes. Blocks 0..511 = proj (16-row tiles); 512..2559 = pack.
// Proj stores h in B-FRAGMENT layout hB[b][jt32][head][cb][lane64][8] (bf16)
// so K2's B-loads are fully coalesced 1KB instructions.
__global__ __launch_bounds__(256) void k01(
    const int* __restrict__ adj, const float* __restrict__ x,
    const float* __restrict__ W, const float* __restrict__ a_l,
    const float* __restrict__ a_r, u64* __restrict__ abits,
    u16* __restrict__ hB, float* __restrict__ el, float* __restrict__ er)
{
    const int t = threadIdx.x;

    if (blockIdx.x >= 512) {
        // ---- pack adj int32 -> bitmask u64[B*N][32], one wave per row ----
        const int wid = ((blockIdx.x - 512) << 2) | (t >> 6);
        const int lane = t & 63;
        const int* rowp = adj + (size_t)wid * NN;
        u64 mym = 0;
#pragma unroll 8
        for (int jt = 0; jt < 32; ++jt) {
            int v = rowp[jt * 64 + lane];
            u64 m = __ballot(v != 0);
            if (lane == jt) mym = m;
        }
        if (lane < 32) abits[(size_t)wid * 32 + lane] = mym;
        return;
    }

    // ---- projection: h = x @ W^T (fp32), el/er (pre-scaled by log2e) ----
    const int b = blockIdx.x >> 7;
    const int n0 = (blockIdx.x & 127) * 16;

    __shared__ __align__(16) float xs[16][F_IN];   // 8 KB
    {
        const f32x4* src = (const f32x4*)(x + ((size_t)b * NN + n0) * F_IN);
        f32x4* dst = (f32x4*)&xs[0][0];
        dst[t] = src[t];
        dst[t + 256] = src[t + 256];
    }
    __syncthreads();

    float acc[16];
#pragma unroll
    for (int n = 0; n < 16; ++n) acc[n] = 0.f;

    const float* wrow = W + (size_t)t * F_IN;
#pragma unroll 2
    for (int k0 = 0; k0 < F_IN; k0 += 8) {
        f32x4 w0 = *(const f32x4*)(wrow + k0);
        f32x4 w1 = *(const f32x4*)(wrow + k0 + 4);
#pragma unroll
        for (int n = 0; n < 16; ++n) {
            f32x4 xa = *(const f32x4*)&xs[n][k0];
            f32x4 xb = *(const f32x4*)&xs[n][k0 + 4];
            float s = acc[n];
            s = fmaf(xa[0], w0[0], s); s = fmaf(xa[1], w0[1], s);
            s = fmaf(xa[2], w0[2], s); s = fmaf(xa[3], w0[3], s);
            s = fmaf(xb[0], w1[0], s); s = fmaf(xb[1], w1[1], s);
            s = fmaf(xb[2], w1[2], s); s = fmaf(xb[3], w1[3], s);
            acc[n] = s;
        }
    }

    const int w = t >> 6, lane = t & 63;
    const float al = a_l[t];
    const float ar = a_r[t];
    float my_el = 0.f, my_er = 0.f;
#pragma unroll
    for (int n = 0; n < 16; ++n) {
        float vl = acc[n] * al;
        float vr = acc[n] * ar;
#pragma unroll
        for (int off = 32; off; off >>= 1) {
            vl += __shfl_xor(vl, off, 64);
            vr += __shfl_xor(vr, off, 64);
        }
        if (lane == n) { my_el = vl; my_er = vr; }
    }
    if (lane < 16) {
        el[((size_t)b * NH + w) * NN + n0 + lane] = my_el * LOG2E;
        er[((size_t)b * NH + w) * NN + n0 + lane] = my_er * LOG2E;
    }

    // B-fragment layout store: thread t = (w, cb, dcol); its 16 n's are
    // j's in 32-tile jt32 = n0>>5, lanes lb/lb+16, elems j&7.
    const int dcol = t & 15, cb = (t >> 4) & 3;
    const int jt32 = n0 >> 5;
    const int lb = dcol + ((n0 >> 3) & 2) * 16;   // n0%32==0 -> +0 ; ==16 -> +32
    u16* hb = hB + ((((size_t)b * 64 + jt32) * 4 + w) * 4 + cb) * 512 + (size_t)lb * 8;
    s16x8 pk0, pk1;
#pragma unroll
    for (int n = 0; n < 8; ++n) pk0[n] = (short)f32_to_bf16_rtn(acc[n]);
#pragma unroll
    for (int n = 0; n < 8; ++n) pk1[n] = (short)f32_to_bf16_rtn(acc[n + 8]);
    *(s16x8*)hb         = pk0;   // lane lb   : j = n0..n0+7
    *(s16x8*)(hb + 128) = pk1;   // lane lb+16: j = n0+8..n0+15
}

// K2: fused masked softmax + aggregation. NO LDS staging, NO in-loop barriers.
// wave = (b, head, 32-row i-tile, j-quarter). 4096 independent waves (50% occ).
// Per iter (32 j): 4 coalesced 1KB B-frag loads + 2 e_r + 2 mask words,
// P-gen in regs, 10 MFMAs. Register dist-1 prefetch. Cross-jq LDS reduce at end.
__global__ __launch_bounds__(256, 4) void k2_attn(
    const uint32_t* __restrict__ abits32, const u16* __restrict__ hB,
    const float* __restrict__ el, const float* __restrict__ er,
    float* __restrict__ out)
{
    const int t = threadIdx.x;
    const int jq = t >> 6, l = t & 63;
    int bid = blockIdx.x;
    bid = (bid & 7) * 128 + (bid >> 3);   // XCD swizzle (1024 % 8 == 0, bijective)
    const int b = bid >> 8;
    const int w = (bid >> 6) & 3;         // head
    const int i0 = (bid & 63) * 32;
    const int r = l & 15;                 // A row / D col
    const int kb = l >> 4;                // k-slice 0..3
    const int ks = kb * 8;
    const int irow0 = i0 + r, irow1 = irow0 + 16;

    // B-frag base: wave's jq chunk starts at tile jq*16; stride 8192 u16/tile.
    const u16* hbp = hB + ((((size_t)b * 64 + jq * 16) * 4 + w) * 4) * 512 + (size_t)l * 8;
    const float* errp = er + ((size_t)b * NH + w) * NN + jq * 512 + ks;
    const uint32_t* m0p = abits32 + ((size_t)b * NN + irow0) * 64 + jq * 16;
    const uint32_t* m1p = abits32 + ((size_t)b * NN + irow1) * 64 + jq * 16;

    const float el_i0 = el[((size_t)b * NH + w) * NN + irow0];
    const float el_i1 = el[((size_t)b * NH + w) * NN + irow1];

    f32x4 a00 = {0.f,0.f,0.f,0.f}, a01 = a00, a02 = a00, a03 = a00, as0 = a00;
    f32x4 a10 = a00, a11 = a00, a12 = a00, a13 = a00, as1 = a00;
    s16x8 ones;
#pragma unroll
    for (int k = 0; k < 8; ++k) ones[k] = (short)0x3F80;   // bf16 1.0

    // prologue: iter-0 operands
    s16x8 b0c = *(const s16x8*)(hbp + 0 * 512);
    s16x8 b1c = *(const s16x8*)(hbp + 1 * 512);
    s16x8 b2c = *(const s16x8*)(hbp + 2 * 512);
    s16x8 b3c = *(const s16x8*)(hbp + 3 * 512);
    f32x4 e0c = *(const f32x4*)errp;
    f32x4 e1c = *(const f32x4*)(errp + 4);
    uint32_t mc0 = m0p[0], mc1 = m1p[0];
    __builtin_amdgcn_sched_barrier(0);

#define MFMA_BF16 __builtin_amdgcn_mfma_f32_16x16x32_bf16
#pragma unroll 2
    for (int it = 0; it < 16; ++it) {
        // dist-1 prefetch of iter it+1
        s16x8 b0n = b0c, b1n = b1c, b2n = b2c, b3n = b3c;
        f32x4 e0n = e0c, e1n = e1c;
        uint32_t mn0 = mc0, mn1 = mc1;
        if (it < 15) {
            const u16* hp = hbp + (size_t)(it + 1) * 8192;
            b0n = *(const s16x8*)(hp + 0 * 512);
            b1n = *(const s16x8*)(hp + 1 * 512);
            b2n = *(const s16x8*)(hp + 2 * 512);
            b3n = *(const s16x8*)(hp + 3 * 512);
            const float* ep = errp + (it + 1) * 32;
            e0n = *(const f32x4*)ep;
            e1n = *(const f32x4*)(ep + 4);
            mn0 = m0p[it + 1];
            mn1 = m1p[it + 1];
        }
        __builtin_amdgcn_sched_barrier(0);

        // P-gen for both 16-row halves (8 j's per lane)
        uint32_t w2a = mc0 >> ks;
        uint32_t w2b = mc1 >> ks;
        uint32_t pua[8], pub[8];
#pragma unroll
        for (int k = 0; k < 8; ++k) {
            float e_j = (k < 4) ? e0c[k] : e1c[k - 4];
            float s0 = el_i0 + e_j;
            float s1 = el_i1 + e_j;
            s0 = fmaxf(s0, 0.2f * s0);
            s1 = fmaxf(s1, 0.2f * s1);
            float p0 = exp2_fast(s0);
            float p1 = exp2_fast(s1);
            union { float f; uint32_t u; } c0, c1; c0.f = p0; c1.f = p1;
            pua[k] = c0.u & (uint32_t)sbfe1(w2a, k);
            pub[k] = c1.u & (uint32_t)sbfe1(w2b, k);
        }
        union { s16x8 v; uint32_t u[4]; } afa, afb;
        afa.u[0] = __builtin_amdgcn_perm(pua[1], pua[0], 0x07060302);
        afa.u[1] = __builtin_amdgcn_perm(pua[3], pua[2], 0x07060302);
        afa.u[2] = __builtin_amdgcn_perm(pua[5], pua[4], 0x07060302);
        afa.u[3] = __builtin_amdgcn_perm(pua[7], pua[6], 0x07060302);
        afb.u[0] = __builtin_amdgcn_perm(pub[1], pub[0], 0x07060302);
        afb.u[1] = __builtin_amdgcn_perm(pub[3], pub[2], 0x07060302);
        afb.u[2] = __builtin_amdgcn_perm(pub[5], pub[4], 0x07060302);
        afb.u[3] = __builtin_amdgcn_perm(pub[7], pub[6], 0x07060302);

        a00 = MFMA_BF16(afa.v, b0c, a00, 0, 0, 0);
        a01 = MFMA_BF16(afa.v, b1c, a01, 0, 0, 0);
        a02 = MFMA_BF16(afa.v, b2c, a02, 0, 0, 0);
        a03 = MFMA_BF16(afa.v, b3c, a03, 0, 0, 0);
        as0 = MFMA_BF16(afa.v, ones, as0, 0, 0, 0);
        a10 = MFMA_BF16(afb.v, b0c, a10, 0, 0, 0);
        a11 = MFMA_BF16(afb.v, b1c, a11, 0, 0, 0);
        a12 = MFMA_BF16(afb.v, b2c, a12, 0, 0, 0);
        a13 = MFMA_BF16(afb.v, b3c, a13, 0, 0, 0);
        as1 = MFMA_BF16(afb.v, ones, as1, 0, 0, 0);

        b0c = b0n; b1c = b1n; b2c = b2n; b3c = b3n;
        e0c = e0n; e1c = e1n; mc0 = mn0; mc1 = mn1;
    }

    // ---- cross-jq reduce through LDS (end-of-kernel only) ----
    __shared__ __align__(16) float racc[3 * 64 * 44];   // 33 KB, 16B-aligned rows
    if (jq > 0) {
        float* p = &racc[((jq - 1) * 64 + l) * 44];
        *(f32x4*)(p +  0) = a00; *(f32x4*)(p +  4) = a01;
        *(f32x4*)(p +  8) = a02; *(f32x4*)(p + 12) = a03;
        *(f32x4*)(p + 16) = as0;
        *(f32x4*)(p + 20) = a10; *(f32x4*)(p + 24) = a11;
        *(f32x4*)(p + 28) = a12; *(f32x4*)(p + 32) = a13;
        *(f32x4*)(p + 36) = as1;
    }
    __syncthreads();
    if (jq == 0) {
#pragma unroll
        for (int s = 0; s < 3; ++s) {
            const float* p = &racc[(s * 64 + l) * 44];
            a00 += *(const f32x4*)(p +  0); a01 += *(const f32x4*)(p +  4);
            a02 += *(const f32x4*)(p +  8); a03 += *(const f32x4*)(p + 12);
            as0 += *(const f32x4*)(p + 16);
            a10 += *(const f32x4*)(p + 20); a11 += *(const f32x4*)(p + 24);
            a12 += *(const f32x4*)(p + 28); a13 += *(const f32x4*)(p + 32);
            as1 += *(const f32x4*)(p + 36);
        }

        float* op = out + ((size_t)b * NN + i0) * F_OUT + w * HD;
#pragma unroll
        for (int q = 0; q < 4; ++q) {
            const int row0 = kb * 4 + q;
            float inv0 = 1.0f / as0[q];
            op[(size_t)row0 * F_OUT +  0 + r] = a00[q] * inv0;
            op[(size_t)row0 * F_OUT + 16 + r] = a01[q] * inv0;
            op[(size_t)row0 * F_OUT + 32 + r] = a02[q] * inv0;
            op[(size_t)row0 * F_OUT + 48 + r] = a03[q] * inv0;
            const int row1 = 16 + kb * 4 + q;
            float inv1 = 1.0f / as1[q];
            op[(size_t)row1 * F_OUT +  0 + r] = a10[q] * inv1;
            op[(size_t)row1 * F_OUT + 16 + r] = a11[q] * inv1;
            op[(size_t)row1 * F_OUT + 32 + r] = a12[q] * inv1;
            op[(size_t)row1 * F_OUT + 48 + r] = a13[q] * inv1;
        }
    }
}

extern "C" void kernel_launch(void* const* d_in, const int* in_sizes, int n_in,
                              void* d_out, int out_size, void* d_ws, size_t ws_size,
                              hipStream_t stream) {
    const float* x   = (const float*)d_in[0];
    const int*   adj = (const int*)d_in[1];
    const float* W   = (const float*)d_in[2];
    const float* a_l = (const float*)d_in[3];
    const float* a_r = (const float*)d_in[4];
    float* out = (float*)d_out;

    char* ws = (char*)d_ws;
    u16*   hB    = (u16*)ws;                                   // 4 MB
    u64*   abits = (u64*)(ws + (size_t)BB * F_OUT * NN * 2);   // 2 MB
    float* el    = (float*)(ws + (size_t)BB * F_OUT * NN * 2 + (size_t)BB * NN * 32 * 8);
    float* er    = el + (size_t)BB * NH * NN;

    k01<<<512 + BB * NN / 4, 256, 0, stream>>>(adj, x, W, a_l, a_r, abits, hB, el, er);
    k2_attn<<<BB * NH * (NN / 32), 256, 0, stream>>>((const uint32_t*)abits, hB, el, er, out);
}

// Round 7
// 50.675 us; speedup vs baseline: 2.3975x; 1.1204x over previous
//
#include <hip/hip_runtime.h>
#include <stdint.h>

#define BB 4
#define NN 2048
#define F_IN 128
#define F_OUT 256
#define NH 4
#define HD 64

typedef float f32x4 __attribute__((ext_vector_type(4)));
typedef short s16x8 __attribute__((ext_vector_type(8)));
typedef int i32x4 __attribute__((ext_vector_type(4)));
typedef unsigned long long u64;
typedef unsigned short u16;

#define LOG2E 1.4426950408889634f

__device__ __forceinline__ u16 f32_to_bf16_rtn(float f) {
    union { float f; uint32_t u; } v; v.f = f;
    uint32_t u = v.u;
    u += 0x7fffu + ((u >> 16) & 1u);
    return (u16)(u >> 16);
}

__device__ __forceinline__ float exp2_fast(float x) {
#if __has_builtin(__builtin_amdgcn_exp2f)
    return __builtin_amdgcn_exp2f(x);
#else
    return exp2f(x);
#endif
}

__device__ __forceinline__ int sbfe1(uint32_t v, int k) {
#if __has_builtin(__builtin_amdgcn_sbfe)
    return __builtin_amdgcn_sbfe((int)v, k, 1);   // bit k sign-extended: 0 or -1
#else
    return ((int32_t)(v << (31 - k))) >> 31;
#endif
}

// K01: fused adj-pack (HBM-streaming) + projection (VALU/LDS) — complementary
// pipes. Blocks 0..511 = proj (16-row tiles); 512..2559 = pack.
// Proj stores h in B-FRAGMENT layout hB[b][jt32][head][cb][lane64][8] (bf16)
// so K2's B-loads are fully coalesced 1KB instructions.
__global__ __launch_bounds__(256) void k01(
    const int* __restrict__ adj, const float* __restrict__ x,
    const float* __restrict__ W, const float* __restrict__ a_l,
    const float* __restrict__ a_r, u64* __restrict__ abits,
    u16* __restrict__ hB, float* __restrict__ el, float* __restrict__ er)
{
    const int t = threadIdx.x;

    if (blockIdx.x >= 512) {
        // ---- pack adj int32 -> bitmask u64[B*N][32], one wave per row ----
        const int wid = ((blockIdx.x - 512) << 2) | (t >> 6);
        const int lane = t & 63;
        const int* rowp = adj + (size_t)wid * NN;
        u64 mym = 0;
#pragma unroll 8
        for (int jt = 0; jt < 32; ++jt) {
            int v = rowp[jt * 64 + lane];
            u64 m = __ballot(v != 0);
            if (lane == jt) mym = m;
        }
        if (lane < 32) abits[(size_t)wid * 32 + lane] = mym;
        return;
    }

    // ---- projection: h = x @ W^T (fp32), el/er (pre-scaled by log2e) ----
    const int b = blockIdx.x >> 7;
    const int n0 = (blockIdx.x & 127) * 16;

    __shared__ __align__(16) float xs[16][F_IN];   // 8 KB
    {
        const f32x4* src = (const f32x4*)(x + ((size_t)b * NN + n0) * F_IN);
        f32x4* dst = (f32x4*)&xs[0][0];
        dst[t] = src[t];
        dst[t + 256] = src[t + 256];
    }
    __syncthreads();

    float acc[16];
#pragma unroll
    for (int n = 0; n < 16; ++n) acc[n] = 0.f;

    const float* wrow = W + (size_t)t * F_IN;
#pragma unroll 2
    for (int k0 = 0; k0 < F_IN; k0 += 8) {
        f32x4 w0 = *(const f32x4*)(wrow + k0);
        f32x4 w1 = *(const f32x4*)(wrow + k0 + 4);
#pragma unroll
        for (int n = 0; n < 16; ++n) {
            f32x4 xa = *(const f32x4*)&xs[n][k0];
            f32x4 xb = *(const f32x4*)&xs[n][k0 + 4];
            float s = acc[n];
            s = fmaf(xa[0], w0[0], s); s = fmaf(xa[1], w0[1], s);
            s = fmaf(xa[2], w0[2], s); s = fmaf(xa[3], w0[3], s);
            s = fmaf(xb[0], w1[0], s); s = fmaf(xb[1], w1[1], s);
            s = fmaf(xb[2], w1[2], s); s = fmaf(xb[3], w1[3], s);
            acc[n] = s;
        }
    }

    const int w = t >> 6, lane = t & 63;
    const float al = a_l[t];
    const float ar = a_r[t];
    float my_el = 0.f, my_er = 0.f;
#pragma unroll
    for (int n = 0; n < 16; ++n) {
        float vl = acc[n] * al;
        float vr = acc[n] * ar;
#pragma unroll
        for (int off = 32; off; off >>= 1) {
            vl += __shfl_xor(vl, off, 64);
            vr += __shfl_xor(vr, off, 64);
        }
        if (lane == n) { my_el = vl; my_er = vr; }
    }
    if (lane < 16) {
        el[((size_t)b * NH + w) * NN + n0 + lane] = my_el * LOG2E;
        er[((size_t)b * NH + w) * NN + n0 + lane] = my_er * LOG2E;
    }

    // B-fragment layout store: thread t = (w, cb, dcol); its 16 n's are
    // j's in 32-tile jt32 = n0>>5, lanes lb/lb+16, elems j&7.
    const int dcol = t & 15, cb = (t >> 4) & 3;
    const int jt32 = n0 >> 5;
    const int lb = dcol + ((n0 >> 3) & 2) * 16;   // n0%32==0 -> +0 ; ==16 -> +32
    u16* hb = hB + ((((size_t)b * 64 + jt32) * 4 + w) * 4 + cb) * 512 + (size_t)lb * 8;
    s16x8 pk0, pk1;
#pragma unroll
    for (int n = 0; n < 8; ++n) pk0[n] = (short)f32_to_bf16_rtn(acc[n]);
#pragma unroll
    for (int n = 0; n < 8; ++n) pk1[n] = (short)f32_to_bf16_rtn(acc[n + 8]);
    *(s16x8*)hb         = pk0;   // lane lb   : j = n0..n0+7
    *(s16x8*)(hb + 128) = pk1;   // lane lb+16: j = n0+8..n0+15
}

// K2: fused masked softmax + aggregation. NO LDS staging, NO in-loop barriers.
// wave = (b, head, 32-row i-tile, j-quarter). launch_bounds(256,3): ~170-VGPR
// budget so the dist-1 B-frag register prefetch actually stays registered.
// Masks gathered as dwordx4 per 4-iter GROUP (dist-1 group prefetch);
// e_r loaded at use (L1-resident broadcast). Cross-jq LDS reduce at end.
__global__ __launch_bounds__(256, 3) void k2_attn(
    const uint32_t* __restrict__ abits32, const u16* __restrict__ hB,
    const float* __restrict__ el, const float* __restrict__ er,
    float* __restrict__ out)
{
    const int t = threadIdx.x;
    const int jq = t >> 6, l = t & 63;
    int bid = blockIdx.x;
    bid = (bid & 7) * 128 + (bid >> 3);   // XCD swizzle (1024 % 8 == 0, bijective)
    const int b = bid >> 8;
    const int w = (bid >> 6) & 3;         // head
    const int i0 = (bid & 63) * 32;
    const int r = l & 15;                 // A row / D col
    const int kb = l >> 4;                // k-slice 0..3
    const int ks = kb * 8;
    const int irow0 = i0 + r, irow1 = irow0 + 16;

    // B-frag base: wave's jq chunk starts at tile jq*16; stride 8192 u16/tile.
    const u16* hbp = hB + ((((size_t)b * 64 + jq * 16) * 4 + w) * 4) * 512 + (size_t)l * 8;
    const float* errp = er + ((size_t)b * NH + w) * NN + jq * 512 + ks;
    const i32x4* m0p4 = (const i32x4*)(abits32 + ((size_t)b * NN + irow0) * 64 + jq * 16);
    const i32x4* m1p4 = (const i32x4*)(abits32 + ((size_t)b * NN + irow1) * 64 + jq * 16);

    const float el_i0 = el[((size_t)b * NH + w) * NN + irow0];
    const float el_i1 = el[((size_t)b * NH + w) * NN + irow1];

    f32x4 a00 = {0.f,0.f,0.f,0.f}, a01 = a00, a02 = a00, a03 = a00, as0 = a00;
    f32x4 a10 = a00, a11 = a00, a12 = a00, a13 = a00, as1 = a00;
    s16x8 ones;
#pragma unroll
    for (int k = 0; k < 8; ++k) ones[k] = (short)0x3F80;   // bf16 1.0

    // prologue: group-0 masks + iter-0 B-frags
    i32x4 mg0c = m0p4[0], mg1c = m1p4[0];
    s16x8 b0c = *(const s16x8*)(hbp + 0 * 512);
    s16x8 b1c = *(const s16x8*)(hbp + 1 * 512);
    s16x8 b2c = *(const s16x8*)(hbp + 2 * 512);
    s16x8 b3c = *(const s16x8*)(hbp + 3 * 512);
    __builtin_amdgcn_sched_barrier(0);

#define MFMA_BF16 __builtin_amdgcn_mfma_f32_16x16x32_bf16
#define BODY(IT, S, PF)                                                       \
    {                                                                         \
        /* e_r at use (L1 broadcast) */                                       \
        const float* ep_ = errp + (IT) * 32;                                  \
        f32x4 e0_ = *(const f32x4*)ep_;                                       \
        f32x4 e1_ = *(const f32x4*)(ep_ + 4);                                 \
        s16x8 b0n, b1n, b2n, b3n;                                             \
        if (PF) { /* dist-1 B prefetch */                                     \
            const u16* hp_ = hbp + (size_t)((IT) + 1) * 8192;                 \
            b0n = *(const s16x8*)(hp_ + 0 * 512);                             \
            b1n = *(const s16x8*)(hp_ + 1 * 512);                             \
            b2n = *(const s16x8*)(hp_ + 2 * 512);                             \
            b3n = *(const s16x8*)(hp_ + 3 * 512);                             \
        }                                                                     \
        __builtin_amdgcn_sched_barrier(0);                                    \
        uint32_t w2a = ((uint32_t)mg0c[S]) >> ks;                             \
        uint32_t w2b = ((uint32_t)mg1c[S]) >> ks;                             \
        uint32_t pua[8], pub[8];                                              \
        _Pragma("unroll")                                                     \
        for (int k = 0; k < 8; ++k) {                                         \
            float e_j = (k < 4) ? e0_[k] : e1_[k - 4];                        \
            float s0 = el_i0 + e_j;                                           \
            float s1 = el_i1 + e_j;                                           \
            s0 = fmaxf(s0, 0.2f * s0);                                        \
            s1 = fmaxf(s1, 0.2f * s1);                                        \
            float p0 = exp2_fast(s0);                                         \
            float p1 = exp2_fast(s1);                                         \
            union { float f; uint32_t u; } c0, c1; c0.f = p0; c1.f = p1;      \
            pua[k] = c0.u & (uint32_t)sbfe1(w2a, k);                          \
            pub[k] = c1.u & (uint32_t)sbfe1(w2b, k);                          \
        }                                                                     \
        union { s16x8 v; uint32_t u[4]; } afa, afb;                           \
        afa.u[0] = __builtin_amdgcn_perm(pua[1], pua[0], 0x07060302);         \
        afa.u[1] = __builtin_amdgcn_perm(pua[3], pua[2], 0x07060302);         \
        afa.u[2] = __builtin_amdgcn_perm(pua[5], pua[4], 0x07060302);         \
        afa.u[3] = __builtin_amdgcn_perm(pua[7], pua[6], 0x07060302);         \
        afb.u[0] = __builtin_amdgcn_perm(pub[1], pub[0], 0x07060302);         \
        afb.u[1] = __builtin_amdgcn_perm(pub[3], pub[2], 0x07060302);         \
        afb.u[2] = __builtin_amdgcn_perm(pub[5], pub[4], 0x07060302);         \
        afb.u[3] = __builtin_amdgcn_perm(pub[7], pub[6], 0x07060302);         \
        a00 = MFMA_BF16(afa.v, b0c, a00, 0, 0, 0);                            \
        a01 = MFMA_BF16(afa.v, b1c, a01, 0, 0, 0);                            \
        a02 = MFMA_BF16(afa.v, b2c, a02, 0, 0, 0);                            \
        a03 = MFMA_BF16(afa.v, b3c, a03, 0, 0, 0);                            \
        as0 = MFMA_BF16(afa.v, ones, as0, 0, 0, 0);                           \
        a10 = MFMA_BF16(afb.v, b0c, a10, 0, 0, 0);                            \
        a11 = MFMA_BF16(afb.v, b1c, a11, 0, 0, 0);                            \
        a12 = MFMA_BF16(afb.v, b2c, a12, 0, 0, 0);                            \
        a13 = MFMA_BF16(afb.v, b3c, a13, 0, 0, 0);                            \
        as1 = MFMA_BF16(afb.v, ones, as1, 0, 0, 0);                           \
        if (PF) { b0c = b0n; b1c = b1n; b2c = b2n; b3c = b3n; }               \
    }

    // groups 0..2: always prefetch next group's masks + next iter's B
    for (int g = 0; g < 3; ++g) {
        i32x4 mg0n = m0p4[g + 1];
        i32x4 mg1n = m1p4[g + 1];
        __builtin_amdgcn_sched_barrier(0);
#pragma unroll
        for (int s = 0; s < 4; ++s) {
            const int it = g * 4 + s;
            BODY(it, s, 1);
        }
        mg0c = mg0n; mg1c = mg1n;
    }
    // group 3: peeled, static prefetch guards
#pragma unroll
    for (int s = 0; s < 4; ++s) {
        const int it = 12 + s;
        if (s < 3) { BODY(it, s, 1); } else { BODY(it, s, 0); }
    }

    // ---- cross-jq reduce through LDS (end-of-kernel only) ----
    __shared__ __align__(16) float racc[3 * 64 * 44];   // 33 KB
    if (jq > 0) {
        float* p = &racc[((jq - 1) * 64 + l) * 44];
        *(f32x4*)(p +  0) = a00; *(f32x4*)(p +  4) = a01;
        *(f32x4*)(p +  8) = a02; *(f32x4*)(p + 12) = a03;
        *(f32x4*)(p + 16) = as0;
        *(f32x4*)(p + 20) = a10; *(f32x4*)(p + 24) = a11;
        *(f32x4*)(p + 28) = a12; *(f32x4*)(p + 32) = a13;
        *(f32x4*)(p + 36) = as1;
    }
    __syncthreads();
    if (jq == 0) {
#pragma unroll
        for (int s = 0; s < 3; ++s) {
            const float* p = &racc[(s * 64 + l) * 44];
            a00 += *(const f32x4*)(p +  0); a01 += *(const f32x4*)(p +  4);
            a02 += *(const f32x4*)(p +  8); a03 += *(const f32x4*)(p + 12);
            as0 += *(const f32x4*)(p + 16);
            a10 += *(const f32x4*)(p + 20); a11 += *(const f32x4*)(p + 24);
            a12 += *(const f32x4*)(p + 28); a13 += *(const f32x4*)(p + 32);
            as1 += *(const f32x4*)(p + 36);
        }

        float* op = out + ((size_t)b * NN + i0) * F_OUT + w * HD;
#pragma unroll
        for (int q = 0; q < 4; ++q) {
            const int row0 = kb * 4 + q;
            float inv0 = 1.0f / as0[q];
            op[(size_t)row0 * F_OUT +  0 + r] = a00[q] * inv0;
            op[(size_t)row0 * F_OUT + 16 + r] = a01[q] * inv0;
            op[(size_t)row0 * F_OUT + 32 + r] = a02[q] * inv0;
            op[(size_t)row0 * F_OUT + 48 + r] = a03[q] * inv0;
            const int row1 = 16 + kb * 4 + q;
            float inv1 = 1.0f / as1[q];
            op[(size_t)row1 * F_OUT +  0 + r] = a10[q] * inv1;
            op[(size_t)row1 * F_OUT + 16 + r] = a11[q] * inv1;
            op[(size_t)row1 * F_OUT + 32 + r] = a12[q] * inv1;
            op[(size_t)row1 * F_OUT + 48 + r] = a13[q] * inv1;
        }
    }
}

extern "C" void kernel_launch(void* const* d_in, const int* in_sizes, int n_in,
                              void* d_out, int out_size, void* d_ws, size_t ws_size,
                              hipStream_t stream) {
    const float* x   = (const float*)d_in[0];
    const int*   adj = (const int*)d_in[1];
    const float* W   = (const float*)d_in[2];
    const float* a_l = (const float*)d_in[3];
    const float* a_r = (const float*)d_in[4];
    float* out = (float*)d_out;

    char* ws = (char*)d_ws;
    u16*   hB    = (u16*)ws;                                   // 4 MB
    u64*   abits = (u64*)(ws + (size_t)BB * F_OUT * NN * 2);   // 2 MB
    float* el    = (float*)(ws + (size_t)BB * F_OUT * NN * 2 + (size_t)BB * NN * 32 * 8);
    float* er    = el + (size_t)BB * NH * NN;

    k01<<<512 + BB * NN / 4, 256, 0, stream>>>(adj, x, W, a_l, a_r, abits, hB, el, er);
    k2_attn<<<BB * NH * (NN / 32), 256, 0, stream>>>((const uint32_t*)abits, hB, el, er, out);
}

// Round 8
// 46.868 us; speedup vs baseline: 2.5923x; 1.0812x over previous
//
#include <hip/hip_runtime.h>
#include <stdint.h>

#define BB 4
#define NN 2048
#define F_IN 128
#define F_OUT 256
#define NH 4
#define HD 64

typedef float f32x4 __attribute__((ext_vector_type(4)));
typedef short s16x8 __attribute__((ext_vector_type(8)));
typedef int i32x4 __attribute__((ext_vector_type(4)));
typedef unsigned long long u64;
typedef unsigned short u16;

#define LOG2E 1.4426950408889634f

__device__ __forceinline__ u16 f32_to_bf16_rtn(float f) {
    union { float f; uint32_t u; } v; v.f = f;
    uint32_t u = v.u;
    u += 0x7fffu + ((u >> 16) & 1u);
    return (u16)(u >> 16);
}

__device__ __forceinline__ float exp2_fast(float x) {
#if __has_builtin(__builtin_amdgcn_exp2f)
    return __builtin_amdgcn_exp2f(x);
#else
    return exp2f(x);
#endif
}

__device__ __forceinline__ int sbfe1(uint32_t v, int k) {
#if __has_builtin(__builtin_amdgcn_sbfe)
    return __builtin_amdgcn_sbfe((int)v, k, 1);   // bit k sign-extended: 0 or -1
#else
    return ((int32_t)(v << (31 - k))) >> 31;
#endif
}

// K01: fused adj-pack (HBM-streaming) + projection (VALU/LDS).
// Blocks 0..511 = proj (16-row tiles); 512..2559 = pack.
// el/er reduce via LDS transpose (4x less DS-pipe than shfl butterfly).
__global__ __launch_bounds__(256) void k01(
    const int* __restrict__ adj, const float* __restrict__ x,
    const float* __restrict__ W, const float* __restrict__ a_l,
    const float* __restrict__ a_r, u64* __restrict__ abits,
    u16* __restrict__ hB, float* __restrict__ el, float* __restrict__ er)
{
    const int t = threadIdx.x;

    __shared__ __align__(16) float xs[16][F_IN];     // 8 KB
    __shared__ __align__(16) float redl[4 * 64 * 20]; // 20 KB (stride 20: 16B-aligned rows)
    __shared__ __align__(16) float redr[4 * 64 * 20]; // 20 KB

    if (blockIdx.x >= 512) {
        // ---- pack adj int32 -> bitmask u64[B*N][32], one wave per row ----
        const int wid = ((blockIdx.x - 512) << 2) | (t >> 6);
        const int lane = t & 63;
        const int* rowp = adj + (size_t)wid * NN;
        u64 mym = 0;
#pragma unroll 8
        for (int jt = 0; jt < 32; ++jt) {
            int v = rowp[jt * 64 + lane];
            u64 m = __ballot(v != 0);
            if (lane == jt) mym = m;
        }
        if (lane < 32) abits[(size_t)wid * 32 + lane] = mym;
        return;
    }

    // ---- projection: h = x @ W^T (fp32), el/er (pre-scaled by log2e) ----
    const int b = blockIdx.x >> 7;
    const int n0 = (blockIdx.x & 127) * 16;

    {
        const f32x4* src = (const f32x4*)(x + ((size_t)b * NN + n0) * F_IN);
        f32x4* dst = (f32x4*)&xs[0][0];
        dst[t] = src[t];
        dst[t + 256] = src[t + 256];
    }
    __syncthreads();

    float acc[16];
#pragma unroll
    for (int n = 0; n < 16; ++n) acc[n] = 0.f;

    const float* wrow = W + (size_t)t * F_IN;
#pragma unroll 2
    for (int k0 = 0; k0 < F_IN; k0 += 8) {
        f32x4 w0 = *(const f32x4*)(wrow + k0);
        f32x4 w1 = *(const f32x4*)(wrow + k0 + 4);
#pragma unroll
        for (int n = 0; n < 16; ++n) {
            f32x4 xa = *(const f32x4*)&xs[n][k0];
            f32x4 xb = *(const f32x4*)&xs[n][k0 + 4];
            float s = acc[n];
            s = fmaf(xa[0], w0[0], s); s = fmaf(xa[1], w0[1], s);
            s = fmaf(xa[2], w0[2], s); s = fmaf(xa[3], w0[3], s);
            s = fmaf(xb[0], w1[0], s); s = fmaf(xb[1], w1[1], s);
            s = fmaf(xb[2], w1[2], s); s = fmaf(xb[3], w1[3], s);
            acc[n] = s;
        }
    }

    // e_l / e_r via LDS transpose reduce.
    const int w = t >> 6, lane = t & 63;
    const float al = a_l[t];
    const float ar = a_r[t];
    {
        float* rl = &redl[((size_t)w * 64 + lane) * 20];
        float* rr = &redr[((size_t)w * 64 + lane) * 20];
#pragma unroll
        for (int q = 0; q < 4; ++q) {
            f32x4 vl, vr;
#pragma unroll
            for (int e = 0; e < 4; ++e) {
                vl[e] = acc[q * 4 + e] * al;
                vr[e] = acc[q * 4 + e] * ar;
            }
            *(f32x4*)(rl + q * 4) = vl;
            *(f32x4*)(rr + q * 4) = vr;
        }
    }
    __syncthreads();
    {
        const int n_ = lane & 15, og = lane >> 4;
        float sl = 0.f, sr = 0.f;
#pragma unroll
        for (int oo = 0; oo < 16; ++oo) {
            const int o = og + 4 * oo;
            sl += redl[((size_t)w * 64 + o) * 20 + n_];
            sr += redr[((size_t)w * 64 + o) * 20 + n_];
        }
        sl += __shfl_xor(sl, 16, 64); sl += __shfl_xor(sl, 32, 64);
        sr += __shfl_xor(sr, 16, 64); sr += __shfl_xor(sr, 32, 64);
        if (lane < 16) {
            el[((size_t)b * NH + w) * NN + n0 + lane] = sl * LOG2E;
            er[((size_t)b * NH + w) * NN + n0 + lane] = sr * LOG2E;
        }
    }

    // B-fragment layout store: hB[b][jt32][head][cb][lane64][8] (bf16)
    const int dcol = t & 15, cb = (t >> 4) & 3;
    const int jt32 = n0 >> 5;
    const int lb = dcol + ((n0 >> 3) & 2) * 16;
    u16* hb = hB + ((((size_t)b * 64 + jt32) * 4 + w) * 4 + cb) * 512 + (size_t)lb * 8;
    s16x8 pk0, pk1;
#pragma unroll
    for (int n = 0; n < 8; ++n) pk0[n] = (short)f32_to_bf16_rtn(acc[n]);
#pragma unroll
    for (int n = 0; n < 8; ++n) pk1[n] = (short)f32_to_bf16_rtn(acc[n + 8]);
    *(s16x8*)hb         = pk0;
    *(s16x8*)(hb + 128) = pk1;
}

// K2: fused masked softmax + aggregation. NO LDS staging, NO in-loop barriers.
// wave = (b, head, 32-row i-tile, j-quarter). launch_bounds(256,3).
// dist-1 register prefetch of B-frags AND e_r (both long-latency streams);
// masks gathered dwordx4 per 4-iter group (dist-4). Cross-jq LDS reduce at end.
__global__ __launch_bounds__(256, 3) void k2_attn(
    const uint32_t* __restrict__ abits32, const u16* __restrict__ hB,
    const float* __restrict__ el, const float* __restrict__ er,
    float* __restrict__ out)
{
    const int t = threadIdx.x;
    const int jq = t >> 6, l = t & 63;
    int bid = blockIdx.x;
    bid = (bid & 7) * 128 + (bid >> 3);   // XCD swizzle (1024 % 8 == 0, bijective)
    const int b = bid >> 8;
    const int w = (bid >> 6) & 3;         // head
    const int i0 = (bid & 63) * 32;
    const int r = l & 15;                 // A row / D col
    const int kb = l >> 4;                // k-slice 0..3
    const int ks = kb * 8;
    const int irow0 = i0 + r, irow1 = irow0 + 16;

    const u16* hbp = hB + ((((size_t)b * 64 + jq * 16) * 4 + w) * 4) * 512 + (size_t)l * 8;
    const float* errp = er + ((size_t)b * NH + w) * NN + jq * 512 + ks;
    const i32x4* m0p4 = (const i32x4*)(abits32 + ((size_t)b * NN + irow0) * 64 + jq * 16);
    const i32x4* m1p4 = (const i32x4*)(abits32 + ((size_t)b * NN + irow1) * 64 + jq * 16);

    const float el_i0 = el[((size_t)b * NH + w) * NN + irow0];
    const float el_i1 = el[((size_t)b * NH + w) * NN + irow1];

    f32x4 a00 = {0.f,0.f,0.f,0.f}, a01 = a00, a02 = a00, a03 = a00, as0 = a00;
    f32x4 a10 = a00, a11 = a00, a12 = a00, a13 = a00, as1 = a00;
    s16x8 ones;
#pragma unroll
    for (int k = 0; k < 8; ++k) ones[k] = (short)0x3F80;   // bf16 1.0

    // prologue: group-0 masks + iter-0 B-frags + iter-0 e_r
    i32x4 mg0c = m0p4[0], mg1c = m1p4[0];
    s16x8 b0c = *(const s16x8*)(hbp + 0 * 512);
    s16x8 b1c = *(const s16x8*)(hbp + 1 * 512);
    s16x8 b2c = *(const s16x8*)(hbp + 2 * 512);
    s16x8 b3c = *(const s16x8*)(hbp + 3 * 512);
    f32x4 e0c = *(const f32x4*)errp;
    f32x4 e1c = *(const f32x4*)(errp + 4);
    __builtin_amdgcn_sched_barrier(0);

#define MFMA_BF16 __builtin_amdgcn_mfma_f32_16x16x32_bf16
#define BODY(IT, S, PF)                                                       \
    {                                                                         \
        s16x8 b0n, b1n, b2n, b3n;                                             \
        f32x4 e0n, e1n;                                                       \
        if (PF) { /* dist-1 prefetch: B-frags + e_r */                        \
            const u16* hp_ = hbp + (size_t)((IT) + 1) * 8192;                 \
            b0n = *(const s16x8*)(hp_ + 0 * 512);                             \
            b1n = *(const s16x8*)(hp_ + 1 * 512);                             \
            b2n = *(const s16x8*)(hp_ + 2 * 512);                             \
            b3n = *(const s16x8*)(hp_ + 3 * 512);                             \
            const float* ep_ = errp + ((IT) + 1) * 32;                        \
            e0n = *(const f32x4*)ep_;                                         \
            e1n = *(const f32x4*)(ep_ + 4);                                   \
        }                                                                     \
        __builtin_amdgcn_sched_barrier(0);                                    \
        uint32_t w2a = ((uint32_t)mg0c[S]) >> ks;                             \
        uint32_t w2b = ((uint32_t)mg1c[S]) >> ks;                             \
        uint32_t pua[8], pub[8];                                              \
        _Pragma("unroll")                                                     \
        for (int k = 0; k < 8; ++k) {                                         \
            float e_j = (k < 4) ? e0c[k] : e1c[k - 4];                        \
            float s0 = el_i0 + e_j;                                           \
            float s1 = el_i1 + e_j;                                           \
            s0 = fmaxf(s0, 0.2f * s0);                                        \
            s1 = fmaxf(s1, 0.2f * s1);                                        \
            float p0 = exp2_fast(s0);                                         \
            float p1 = exp2_fast(s1);                                         \
            union { float f; uint32_t u; } c0, c1; c0.f = p0; c1.f = p1;      \
            pua[k] = c0.u & (uint32_t)sbfe1(w2a, k);                          \
            pub[k] = c1.u & (uint32_t)sbfe1(w2b, k);                          \
        }                                                                     \
        union { s16x8 v; uint32_t u[4]; } afa, afb;                           \
        afa.u[0] = __builtin_amdgcn_perm(pua[1], pua[0], 0x07060302);         \
        afa.u[1] = __builtin_amdgcn_perm(pua[3], pua[2], 0x07060302);         \
        afa.u[2] = __builtin_amdgcn_perm(pua[5], pua[4], 0x07060302);         \
        afa.u[3] = __builtin_amdgcn_perm(pua[7], pua[6], 0x07060302);         \
        afb.u[0] = __builtin_amdgcn_perm(pub[1], pub[0], 0x07060302);         \
        afb.u[1] = __builtin_amdgcn_perm(pub[3], pub[2], 0x07060302);         \
        afb.u[2] = __builtin_amdgcn_perm(pub[5], pub[4], 0x07060302);         \
        afb.u[3] = __builtin_amdgcn_perm(pub[7], pub[6], 0x07060302);         \
        a00 = MFMA_BF16(afa.v, b0c, a00, 0, 0, 0);                            \
        a01 = MFMA_BF16(afa.v, b1c, a01, 0, 0, 0);                            \
        a02 = MFMA_BF16(afa.v, b2c, a02, 0, 0, 0);                            \
        a03 = MFMA_BF16(afa.v, b3c, a03, 0, 0, 0);                            \
        as0 = MFMA_BF16(afa.v, ones, as0, 0, 0, 0);                           \
        a10 = MFMA_BF16(afb.v, b0c, a10, 0, 0, 0);                            \
        a11 = MFMA_BF16(afb.v, b1c, a11, 0, 0, 0);                            \
        a12 = MFMA_BF16(afb.v, b2c, a12, 0, 0, 0);                            \
        a13 = MFMA_BF16(afb.v, b3c, a13, 0, 0, 0);                            \
        as1 = MFMA_BF16(afb.v, ones, as1, 0, 0, 0);                           \
        if (PF) { b0c = b0n; b1c = b1n; b2c = b2n; b3c = b3n;                 \
                  e0c = e0n; e1c = e1n; }                                     \
    }

    // groups 0..2: prefetch next group's masks; dist-1 B + e_r inside bodies
    for (int g = 0; g < 3; ++g) {
        i32x4 mg0n = m0p4[g + 1];
        i32x4 mg1n = m1p4[g + 1];
        __builtin_amdgcn_sched_barrier(0);
#pragma unroll
        for (int s = 0; s < 4; ++s) {
            const int it = g * 4 + s;
            BODY(it, s, 1);
        }
        mg0c = mg0n; mg1c = mg1n;
    }
    // group 3: peeled, static prefetch guards
#pragma unroll
    for (int s = 0; s < 4; ++s) {
        const int it = 12 + s;
        if (s < 3) { BODY(it, s, 1); } else { BODY(it, s, 0); }
    }

    // ---- cross-jq reduce through LDS (end-of-kernel only) ----
    __shared__ __align__(16) float racc[3 * 64 * 44];   // 33 KB
    if (jq > 0) {
        float* p = &racc[((jq - 1) * 64 + l) * 44];
        *(f32x4*)(p +  0) = a00; *(f32x4*)(p +  4) = a01;
        *(f32x4*)(p +  8) = a02; *(f32x4*)(p + 12) = a03;
        *(f32x4*)(p + 16) = as0;
        *(f32x4*)(p + 20) = a10; *(f32x4*)(p + 24) = a11;
        *(f32x4*)(p + 28) = a12; *(f32x4*)(p + 32) = a13;
        *(f32x4*)(p + 36) = as1;
    }
    __syncthreads();
    if (jq == 0) {
#pragma unroll
        for (int s = 0; s < 3; ++s) {
            const float* p = &racc[(s * 64 + l) * 44];
            a00 += *(const f32x4*)(p +  0); a01 += *(const f32x4*)(p +  4);
            a02 += *(const f32x4*)(p +  8); a03 += *(const f32x4*)(p + 12);
            as0 += *(const f32x4*)(p + 16);
            a10 += *(const f32x4*)(p + 20); a11 += *(const f32x4*)(p + 24);
            a12 += *(const f32x4*)(p + 28); a13 += *(const f32x4*)(p + 32);
            as1 += *(const f32x4*)(p + 36);
        }

        float* op = out + ((size_t)b * NN + i0) * F_OUT + w * HD;
#pragma unroll
        for (int q = 0; q < 4; ++q) {
            const int row0 = kb * 4 + q;
            float inv0 = 1.0f / as0[q];
            op[(size_t)row0 * F_OUT +  0 + r] = a00[q] * inv0;
            op[(size_t)row0 * F_OUT + 16 + r] = a01[q] * inv0;
            op[(size_t)row0 * F_OUT + 32 + r] = a02[q] * inv0;
            op[(size_t)row0 * F_OUT + 48 + r] = a03[q] * inv0;
            const int row1 = 16 + kb * 4 + q;
            float inv1 = 1.0f / as1[q];
            op[(size_t)row1 * F_OUT +  0 + r] = a10[q] * inv1;
            op[(size_t)row1 * F_OUT + 16 + r] = a11[q] * inv1;
            op[(size_t)row1 * F_OUT + 32 + r] = a12[q] * inv1;
            op[(size_t)row1 * F_OUT + 48 + r] = a13[q] * inv1;
        }
    }
}

extern "C" void kernel_launch(void* const* d_in, const int* in_sizes, int n_in,
                              void* d_out, int out_size, void* d_ws, size_t ws_size,
                              hipStream_t stream) {
    const float* x   = (const float*)d_in[0];
    const int*   adj = (const int*)d_in[1];
    const float* W   = (const float*)d_in[2];
    const float* a_l = (const float*)d_in[3];
    const float* a_r = (const float*)d_in[4];
    float* out = (float*)d_out;

    char* ws = (char*)d_ws;
    u16*   hB    = (u16*)ws;                                   // 4 MB
    u64*   abits = (u64*)(ws + (size_t)BB * F_OUT * NN * 2);   // 2 MB
    float* el    = (float*)(ws + (size_t)BB * F_OUT * NN * 2 + (size_t)BB * NN * 32 * 8);
    float* er    = el + (size_t)BB * NH * NN;

    k01<<<512 + BB * NN / 4, 256, 0, stream>>>(adj, x, W, a_l, a_r, abits, hB, el, er);
    k2_attn<<<BB * NH * (NN / 32), 256, 0, stream>>>((const uint32_t*)abits, hB, el, er, out);
}